// Round 1
// baseline (1056.647 us; speedup 1.0000x reference)
//
#include <hip/hip_runtime.h>
#include <math.h>

#define CC 248
#define MM 65536
#define NN 1024
#define NBATCH 2
#define NCHUNK 32
#define INV_TEMP 100.0f

// ---------------- workspace layout (floats) ----------------
// inv_src : NBATCH*MM      (131072)
// inv_tgt : NBATCH*NN      (2048)
// partials: NBATCH*NN*NCHUNK*4  (262144)  -- (max, Z, Su, Sv) per (b,n,chunk)

__global__ void norm_src_kernel(const float* __restrict__ dense, float* __restrict__ inv_src) {
    int gid = blockIdx.x * 256 + threadIdx.x;   // 0..131071
    int bb = gid >> 16;
    int m  = gid & (MM - 1);
    const float* p = dense + (size_t)(2 * bb) * CC * MM + m;
    float s = 0.f;
#pragma unroll 8
    for (int c = 0; c < CC; ++c) {
        float v = p[(size_t)c * MM];
        s += v * v;
    }
    inv_src[gid] = 1.0f / fmaxf(sqrtf(s), 1e-12f);
}

__global__ void norm_tgt_kernel(const float* __restrict__ kdesc, float* __restrict__ inv_tgt) {
    int gid = blockIdx.x * 256 + threadIdx.x;   // 0..2047
    int bb = gid >> 10;
    int n  = gid & (NN - 1);
    const float* p = kdesc + (size_t)(2 * bb + 1) * CC * NN + n;
    float s = 0.f;
#pragma unroll 8
    for (int c = 0; c < CC; ++c) {
        float v = p[(size_t)c * NN];
        s += v * v;
    }
    inv_tgt[gid] = 1.0f / fmaxf(sqrtf(s), 1e-12f);
}

// Workgroup: (batch, n-tile of 64 rows, m-chunk of 2048 cols).
// Thread: mg = tid&31 owns 4 m-cols, ng = tid>>5 owns 8 n-rows -> 8x4 fp32 acc.
__global__ __launch_bounds__(256, 2)
void score_kernel(const float* __restrict__ dense,
                  const float* __restrict__ kdesc,
                  const float* __restrict__ inv_src,
                  const float* __restrict__ inv_tgt,
                  float* __restrict__ partials) {
    __shared__ float a_lds[CC][64];

    // XCD-aware decode: all 16 n-tiles of a given chunk land on the same XCD
    // (dispatch round-robins blockIdx % 8 across XCDs).
    const int flat = blockIdx.x;          // 0..1023
    const int b    = flat >> 9;
    const int f2   = flat & 511;
    const int xcd  = f2 & 7;
    const int slot = f2 >> 3;             // 0..63
    const int chunk = xcd + 8 * (slot >> 4);  // 0..31
    const int ntile = slot & 15;

    const int tid = threadIdx.x;
    const int mg = tid & 31;
    const int ng = tid >> 5;
    const int n0 = ntile * 64;

    {   // stage A tile (64 rows x 248 C), fold in inv_tgt
        const float* kb  = kdesc + (size_t)(2 * b + 1) * CC * NN + n0;
        const float* itg = inv_tgt + b * NN + n0;
        for (int i = tid; i < CC * 64; i += 256) {
            int c = i >> 6;
            int n = i & 63;
            a_lds[c][n] = kb[(size_t)c * NN + n] * itg[n];
        }
    }
    __syncthreads();

    const float* src = dense + (size_t)(2 * b) * CC * MM;
    const int mchunk0 = chunk * 2048;

    float run_m[8], run_z[8], run_su[8], run_sv[8];
#pragma unroll
    for (int r = 0; r < 8; ++r) { run_m[r] = -INFINITY; run_z[r] = 0.f; run_su[r] = 0.f; run_sv[r] = 0.f; }

    for (int tile = 0; tile < 16; ++tile) {
        const int m_base = mchunk0 + tile * 128;
        float acc[8][4];
#pragma unroll
        for (int r = 0; r < 8; ++r)
#pragma unroll
            for (int j = 0; j < 4; ++j) acc[r][j] = 0.f;

        // K loop with 2-deep register prefetch of the B float4.
        // Overreading 2 rows past c=247 stays inside frames 1..3 (safe).
        const float* sp = src + m_base + mg * 4;
        float4 b0 = *(const float4*)sp;
        float4 b1 = *(const float4*)(sp + (size_t)MM);
        sp += 2 * (size_t)MM;

#pragma unroll 4
        for (int c = 0; c < CC; ++c) {
            float4 bn = *(const float4*)sp;
            sp += (size_t)MM;
            float av[8];
            *(float4*)&av[0] = *(const float4*)&a_lds[c][ng * 8];
            *(float4*)&av[4] = *(const float4*)&a_lds[c][ng * 8 + 4];
            float bvv[4] = { b0.x, b0.y, b0.z, b0.w };
#pragma unroll
            for (int r = 0; r < 8; ++r)
#pragma unroll
                for (int j = 0; j < 4; ++j)
                    acc[r][j] = fmaf(av[r], bvv[j], acc[r][j]);
            b0 = b1; b1 = bn;
        }

        // per-tile softmax partial (online across tiles)
        float4 iv = *(const float4*)(inv_src + (size_t)b * MM + m_base + mg * 4);
        float isc[4] = { iv.x * INV_TEMP, iv.y * INV_TEMP, iv.z * INV_TEMP, iv.w * INV_TEMP };
        float uf[4], vf[4];
#pragma unroll
        for (int j = 0; j < 4; ++j) {
            int mglob = m_base + mg * 4 + j;
            uf[j] = (float)(mglob & 255);
            vf[j] = (float)(mglob >> 8);
        }
#pragma unroll
        for (int r = 0; r < 8; ++r) {
            float s0 = acc[r][0] * isc[0];
            float s1 = acc[r][1] * isc[1];
            float s2 = acc[r][2] * isc[2];
            float s3 = acc[r][3] * isc[3];
            float tmax = fmaxf(fmaxf(s0, s1), fmaxf(s2, s3));
#pragma unroll
            for (int mask = 16; mask >= 1; mask >>= 1)
                tmax = fmaxf(tmax, __shfl_xor(tmax, mask, 64));
            float e0 = __expf(s0 - tmax), e1 = __expf(s1 - tmax);
            float e2 = __expf(s2 - tmax), e3 = __expf(s3 - tmax);
            float tz  = e0 + e1 + e2 + e3;
            float tsu = e0 * uf[0] + e1 * uf[1] + e2 * uf[2] + e3 * uf[3];
            float tsv = e0 * vf[0] + e1 * vf[1] + e2 * vf[2] + e3 * vf[3];
#pragma unroll
            for (int mask = 16; mask >= 1; mask >>= 1) {
                tz  += __shfl_xor(tz,  mask, 64);
                tsu += __shfl_xor(tsu, mask, 64);
                tsv += __shfl_xor(tsv, mask, 64);
            }
            float nm  = fmaxf(run_m[r], tmax);
            float f1  = __expf(run_m[r] - nm);
            float f2e = __expf(tmax - nm);
            run_z[r]  = run_z[r]  * f1 + tz  * f2e;
            run_su[r] = run_su[r] * f1 + tsu * f2e;
            run_sv[r] = run_sv[r] * f1 + tsv * f2e;
            run_m[r]  = nm;
        }
    }

    if (mg == 0) {
#pragma unroll
        for (int r = 0; r < 8; ++r) {
            int n = n0 + ng * 8 + r;
            float4* pp = (float4*)partials + ((size_t)(b * NN + n) * NCHUNK + chunk);
            *pp = make_float4(run_m[r], run_z[r], run_su[r], run_sv[r]);
        }
    }
}

__global__ void combine_kernel(const float* __restrict__ partials,
                               const float* __restrict__ kscores,
                               const float* __restrict__ times,
                               float* __restrict__ out) {
    int gid = blockIdx.x * 256 + threadIdx.x;  // 0..2047 = (b, n)
    int b = gid >> 10;
    int n = gid & (NN - 1);
    const float4* pp = (const float4*)partials + (size_t)gid * NCHUNK;
    float gm = -INFINITY;
#pragma unroll 8
    for (int k = 0; k < NCHUNK; ++k) gm = fmaxf(gm, pp[k].x);
    float Z = 0.f, Su = 0.f, Sv = 0.f;
#pragma unroll 8
    for (int k = 0; k < NCHUNK; ++k) {
        float4 p = pp[k];
        float f = __expf(p.x - gm);
        Z += p.y * f; Su += p.z * f; Sv += p.w * f;
    }
    float u = Su / Z, v = Sv / Z;

    // output 0: pseudo_coords [2,1024,2]
    out[(size_t)gid * 2 + 0] = u;
    out[(size_t)gid * 2 + 1] = v;
    // output 1: keypoint_scores[tgt_ids] [2,1,1024]
    out[4096 + gid] = kscores[(size_t)(2 * b + 1) * NN + n];
    // output 2: tgt_ids [2] = {1, 3}
    if (gid == 0) { out[6144] = 1.0f; out[6145] = 3.0f; }

    // output 3: bilinear sample of src times at (u, v), align_corners semantics
    const float* timg = times + (size_t)(2 * b) * MM;
    float u0 = fminf(fmaxf(floorf(u), 0.f), 255.f);
    float v0 = fminf(fmaxf(floorf(v), 0.f), 255.f);
    float u1 = fminf(u0 + 1.f, 255.f);
    float v1 = fminf(v0 + 1.f, 255.f);
    float au = u - u0, av = v - v0;
    int u0i = (int)u0, u1i = (int)u1, v0i = (int)v0, v1i = (int)v1;
    float t00 = timg[v0i * 256 + u0i], t01 = timg[v0i * 256 + u1i];
    float t10 = timg[v1i * 256 + u0i], t11 = timg[v1i * 256 + u1i];
    float t = t00 * (1.f - au) * (1.f - av) + t01 * au * (1.f - av)
            + t10 * (1.f - au) * av + t11 * au * av;
    out[6146 + gid] = t;
}

extern "C" void kernel_launch(void* const* d_in, const int* in_sizes, int n_in,
                              void* d_out, int out_size, void* d_ws, size_t ws_size,
                              hipStream_t stream) {
    const float* kscores = (const float*)d_in[0];
    const float* kdesc   = (const float*)d_in[1];
    const float* dense   = (const float*)d_in[2];
    const float* times   = (const float*)d_in[3];
    float* out = (float*)d_out;

    float* inv_src  = (float*)d_ws;                 // 131072 floats
    float* inv_tgt  = inv_src + NBATCH * MM;        // 2048 floats
    float* partials = inv_tgt + NBATCH * NN;        // 262144 floats

    hipLaunchKernelGGL(norm_src_kernel, dim3(512),  dim3(256), 0, stream, dense, inv_src);
    hipLaunchKernelGGL(norm_tgt_kernel, dim3(8),    dim3(256), 0, stream, kdesc, inv_tgt);
    hipLaunchKernelGGL(score_kernel,    dim3(1024), dim3(256), 0, stream,
                       dense, kdesc, inv_src, inv_tgt, partials);
    hipLaunchKernelGGL(combine_kernel,  dim3(8),    dim3(256), 0, stream,
                       partials, kscores, times, out);
}

// Round 2
// 670.675 us; speedup vs baseline: 1.5755x; 1.5755x over previous
//
#include <hip/hip_runtime.h>
#include <math.h>

typedef _Float16 f16;
typedef _Float16 f16x8 __attribute__((ext_vector_type(8)));
typedef float f32x4 __attribute__((ext_vector_type(4)));

#define CC 248
#define KP 256
#define MM 65536
#define NN 1024
#define BM 64
#define BN 128
#define KB 64
#define MCH 1024
#define NCHUNKS 64            // MM/MCH
#define MT_PER 8              // MCH/BN
#define SLICES 32             // MT_PER * KP/KB
#define PART_PER 256          // NCHUNKS*4 wavecols

// ---------------- convert B: norm + fp16 hi/lo split + transpose to [m][k] ----------------
__global__ __launch_bounds__(256, 2)
void convB_kernel(const float* __restrict__ dense,
                  f16* __restrict__ bhi, f16* __restrict__ blo,
                  float* __restrict__ inv_src) {
    __shared__ f16 thi[64][256];
    __shared__ f16 tlo[64][256];
    const int bid = blockIdx.x;            // 0..2047
    const int fb  = bid >> 10;             // 0..1 (frames 0,2)
    const int m0  = (bid & 1023) * 64;
    const int tid = threadIdx.x;
    const int cl  = tid >> 6;              // 0..3
    const int ml  = tid & 63;

    const float* dptr = dense + (size_t)(2 * fb) * CC * MM + m0 + ml;
    float ss = 0.f;
    for (int c = cl; c < CC; c += 4) {
        float v = dptr[(size_t)c * MM];
        ss += v * v;
        f16 h = (f16)v;
        float rest = v - (float)h;
        thi[ml][c] = h;
        tlo[ml][c] = (f16)(rest * 2048.0f);
    }
    // stash fp32 partial sums in the (not yet zeroed) pad bytes of thi row
    float* pad = (float*)&thi[ml][248];
    pad[cl] = ss;
    __syncthreads();
    if (cl == 0) {
        float s = pad[0] + pad[1] + pad[2] + pad[3];
        inv_src[(size_t)fb * MM + m0 + ml] = 1.0f / fmaxf(sqrtf(s), 1e-12f);
    }
    __syncthreads();
    thi[ml][248 + cl * 2] = (f16)0.f; thi[ml][249 + cl * 2] = (f16)0.f;
    tlo[ml][248 + cl * 2] = (f16)0.f; tlo[ml][249 + cl * 2] = (f16)0.f;
    __syncthreads();
    f16* outh = bhi + ((size_t)fb * MM + m0) * KP;
    f16* outl = blo + ((size_t)fb * MM + m0) * KP;
#pragma unroll
    for (int it = 0; it < 8; ++it) {
        int id = tid + it * 256;           // 0..2047 chunks of 16B
        int row = id >> 5, j = id & 31;
        *(f16x8*)&outh[(size_t)row * KP + j * 8] = *(const f16x8*)&thi[row][j * 8];
        *(f16x8*)&outl[(size_t)row * KP + j * 8] = *(const f16x8*)&tlo[row][j * 8];
    }
}

// ---------------- convert A: fold inv_tgt, fp16 hi/lo split ----------------
__global__ void convA_kernel(const float* __restrict__ kdesc,
                             f16* __restrict__ ahi, f16* __restrict__ alo) {
    int gid = blockIdx.x * 256 + threadIdx.x;   // 0..2047
    int b = gid >> 10, n = gid & 1023;
    const float* p = kdesc + (size_t)(2 * b + 1) * CC * NN + n;
    float ss = 0.f;
    for (int c = 0; c < CC; ++c) { float v = p[(size_t)c * NN]; ss += v * v; }
    float inv = 1.0f / fmaxf(sqrtf(ss), 1e-12f);
    f16* oh = ahi + (size_t)gid * KP;
    f16* ol = alo + (size_t)gid * KP;
    for (int c = 0; c < CC; ++c) {
        float a = p[(size_t)c * NN] * inv;
        f16 h = (f16)a;
        float rest = a - (float)h;
        oh[c] = h; ol[c] = (f16)(rest * 2048.0f);
    }
    for (int c = CC; c < KP; ++c) { oh[c] = (f16)0.f; ol[c] = (f16)0.f; }
}

// ---------------- fused split-fp16 MFMA GEMM + online softmax ----------------
// LDS layout (bytes):
//   A: plane*32768 + row*512 + (J ^ (row&7))*16          (hi plane0 / lo plane1), J=k/8
//   B: 65536 + buf*32768 + plane*16384 + row*128 + (jj ^ (row&7))*16, jj=k_in_slice/8
__global__ __launch_bounds__(512, 2)
void gemm_kernel(const f16* __restrict__ bhi, const f16* __restrict__ blo,
                 const f16* __restrict__ ahi, const f16* __restrict__ alo,
                 const float* __restrict__ inv_src,
                 float* __restrict__ partials) {
    extern __shared__ char lds[];

    const int bid  = blockIdx.x;           // 0..2047
    const int xcd  = bid & 7;
    const int slot = bid >> 3;             // 0..255
    const int ntile = slot & 15;
    const int pix   = slot >> 4;           // 0..15
    const int g     = xcd + 8 * pix;       // pair id 0..127
    const int b     = g >> 6;
    const int chunk = g & 63;

    const int tid  = threadIdx.x;
    const int lane = tid & 63;
    const int wid  = tid >> 6;             // 0..7
    const int wm   = wid >> 2;             // 0..1
    const int wn   = wid & 3;              // 0..3
    const int n0   = ntile * BM;
    const int m0   = chunk * MCH;

    // ---- stage A (hi+lo), swizzled ds_write ----
    {
        const size_t abase = ((size_t)b * NN + n0) * KP;
#pragma unroll
        for (int it = 0; it < 8; ++it) {
            int plane = it >> 2;
            int id2 = tid + (it & 3) * 512;       // 0..2047
            int row = id2 >> 5, j = id2 & 31;
            const f16* src = (plane ? alo : ahi) + abase + (size_t)row * KP + j * 8;
            f16x8 v = *(const f16x8*)src;
            *(f16x8*)&lds[plane * 32768 + row * 512 + ((j ^ (row & 7)) * 16)] = v;
        }
    }

    auto STAGE = [&](int buf, int s) {
        int mt = s >> 2, ks = s & 3;
        const size_t rowbase = (size_t)b * MM + m0 + mt * BN;
#pragma unroll
        for (int plane = 0; plane < 2; ++plane) {
            const f16* gb = plane ? blo : bhi;
#pragma unroll
            for (int q = 0; q < 2; ++q) {
                int cc  = wid + q * 8;             // 1KB chunk id 0..15
                int row = cc * 8 + (lane >> 3);
                int j   = lane & 7;
                int jsw = j ^ (row & 7);           // pre-swizzled source
                const f16* src = gb + (rowbase + row) * KP + ks * KB + jsw * 8;
                char* dst = &lds[65536 + buf * 32768 + plane * 16384 + cc * 1024];
                __builtin_amdgcn_global_load_lds(
                    (const __attribute__((address_space(1))) void*)src,
                    (__attribute__((address_space(3))) void*)dst, 16, 0, 0);
            }
        }
    };

    f32x4 accH[2][2], accX[2][2];
    float runm[2][4], runz[2][4], runsu[2][4], runsv[2][4];
#pragma unroll
    for (int ap = 0; ap < 2; ++ap) {
#pragma unroll
        for (int bp = 0; bp < 2; ++bp) { accH[ap][bp] = (f32x4){0.f,0.f,0.f,0.f}; accX[ap][bp] = (f32x4){0.f,0.f,0.f,0.f}; }
#pragma unroll
        for (int r = 0; r < 4; ++r) { runm[ap][r] = -INFINITY; runz[ap][r] = 0.f; runsu[ap][r] = 0.f; runsv[ap][r] = 0.f; }
    }

    STAGE(0, 0);
    __syncthreads();

    for (int s = 0; s < SLICES; ++s) {
        if (s + 1 < SLICES) STAGE((s + 1) & 1, s + 1);

        {   // compute slice s
            const int buf = s & 1, ks = s & 3;
#pragma unroll
            for (int t = 0; t < 2; ++t) {
                f16x8 aH[2], aL[2], bH[2], bL[2];
#pragma unroll
                for (int ap = 0; ap < 2; ++ap) {
                    int row = wm * 32 + ap * 16 + (lane & 15);
                    int J = ks * 8 + t * 4 + (lane >> 4);
                    int off = row * 512 + ((J ^ (row & 7)) * 16);
                    aH[ap] = *(const f16x8*)&lds[off];
                    aL[ap] = *(const f16x8*)&lds[32768 + off];
                }
#pragma unroll
                for (int bp = 0; bp < 2; ++bp) {
                    int row = wn * 32 + bp * 16 + (lane & 15);
                    int jj = t * 4 + (lane >> 4);
                    int off = 65536 + buf * 32768 + row * 128 + ((jj ^ (row & 7)) * 16);
                    bH[bp] = *(const f16x8*)&lds[off];
                    bL[bp] = *(const f16x8*)&lds[off + 16384];
                }
#pragma unroll
                for (int ap = 0; ap < 2; ++ap)
#pragma unroll
                    for (int bp = 0; bp < 2; ++bp) {
                        accH[ap][bp] = __builtin_amdgcn_mfma_f32_16x16x32_f16(aH[ap], bH[bp], accH[ap][bp], 0, 0, 0);
                        accX[ap][bp] = __builtin_amdgcn_mfma_f32_16x16x32_f16(aH[ap], bL[bp], accX[ap][bp], 0, 0, 0);
                        accX[ap][bp] = __builtin_amdgcn_mfma_f32_16x16x32_f16(aL[ap], bH[bp], accX[ap][bp], 0, 0, 0);
                    }
            }
        }

        if ((s & 3) == 3) {   // epilogue for finished m-tile
            const int mt = s >> 2;
            float sc[2], uu[2], vv[2];
#pragma unroll
            for (int bp = 0; bp < 2; ++bp) {
                int mg = m0 + mt * BN + wn * 32 + bp * 16 + (lane & 15);
                sc[bp] = inv_src[(size_t)b * MM + mg] * 100.0f;
                uu[bp] = (float)(mg & 255);
                vv[bp] = (float)(mg >> 8);
            }
#pragma unroll
            for (int ap = 0; ap < 2; ++ap) {
#pragma unroll
                for (int r = 0; r < 4; ++r) {
                    float s0 = (accH[ap][0][r] + accX[ap][0][r] * (1.0f/2048.0f)) * sc[0];
                    float s1 = (accH[ap][1][r] + accX[ap][1][r] * (1.0f/2048.0f)) * sc[1];
                    float mx = fmaxf(s0, s1);
#pragma unroll
                    for (int msk = 8; msk >= 1; msk >>= 1) mx = fmaxf(mx, __shfl_xor(mx, msk, 64));
                    float e0 = __expf(s0 - mx), e1 = __expf(s1 - mx);
                    float tz  = e0 + e1;
                    float tsu = e0 * uu[0] + e1 * uu[1];
                    float tsv = e0 * vv[0] + e1 * vv[1];
#pragma unroll
                    for (int msk = 8; msk >= 1; msk >>= 1) {
                        tz  += __shfl_xor(tz,  msk, 64);
                        tsu += __shfl_xor(tsu, msk, 64);
                        tsv += __shfl_xor(tsv, msk, 64);
                    }
                    float nm = fmaxf(runm[ap][r], mx);
                    float f1 = __expf(runm[ap][r] - nm);
                    float f2 = __expf(mx - nm);
                    runz[ap][r]  = runz[ap][r]  * f1 + tz  * f2;
                    runsu[ap][r] = runsu[ap][r] * f1 + tsu * f2;
                    runsv[ap][r] = runsv[ap][r] * f1 + tsv * f2;
                    runm[ap][r]  = nm;
                }
#pragma unroll
                for (int bp = 0; bp < 2; ++bp) { accH[ap][bp] = (f32x4){0.f,0.f,0.f,0.f}; accX[ap][bp] = (f32x4){0.f,0.f,0.f,0.f}; }
            }
        }
        __syncthreads();
    }

    if ((lane & 15) == 0) {
        int g4 = lane >> 4;
#pragma unroll
        for (int ap = 0; ap < 2; ++ap)
#pragma unroll
            for (int r = 0; r < 4; ++r) {
                int nloc = wm * 32 + ap * 16 + g4 * 4 + r;
                size_t idx = (((size_t)b * NN + n0 + nloc) * NCHUNKS + chunk) * 4 + wn;
                ((float4*)partials)[idx] = make_float4(runm[ap][r], runz[ap][r], runsu[ap][r], runsv[ap][r]);
            }
    }
}

// ---------------- combine partials + bilinear + outputs ----------------
__global__ void combine_kernel(const float* __restrict__ partials,
                               const float* __restrict__ kscores,
                               const float* __restrict__ times,
                               float* __restrict__ out) {
    int gid = blockIdx.x * 256 + threadIdx.x;  // 0..2047 = (b, n)
    int b = gid >> 10;
    const float4* pp = (const float4*)partials + (size_t)gid * PART_PER;
    float gm = -INFINITY;
#pragma unroll 8
    for (int k = 0; k < PART_PER; ++k) gm = fmaxf(gm, pp[k].x);
    float Z = 0.f, Su = 0.f, Sv = 0.f;
#pragma unroll 8
    for (int k = 0; k < PART_PER; ++k) {
        float4 p = pp[k];
        float f = __expf(p.x - gm);
        Z += p.y * f; Su += p.z * f; Sv += p.w * f;
    }
    float u = Su / Z, v = Sv / Z;

    out[(size_t)gid * 2 + 0] = u;
    out[(size_t)gid * 2 + 1] = v;
    out[4096 + gid] = kscores[(size_t)(((gid >> 10) * 2) + 1) * NN + (gid & 1023)];
    if (gid == 0) { out[6144] = 1.0f; out[6145] = 3.0f; }

    const float* timg = times + (size_t)(2 * b) * MM;
    float u0 = fminf(fmaxf(floorf(u), 0.f), 255.f);
    float v0 = fminf(fmaxf(floorf(v), 0.f), 255.f);
    float u1 = fminf(u0 + 1.f, 255.f);
    float v1 = fminf(v0 + 1.f, 255.f);
    float au = u - u0, av = v - v0;
    int u0i = (int)u0, u1i = (int)u1, v0i = (int)v0, v1i = (int)v1;
    float t00 = timg[v0i * 256 + u0i], t01 = timg[v0i * 256 + u1i];
    float t10 = timg[v1i * 256 + u0i], t11 = timg[v1i * 256 + u1i];
    float t = t00 * (1.f - au) * (1.f - av) + t01 * au * (1.f - av)
            + t10 * (1.f - au) * av + t11 * au * av;
    out[6146 + gid] = t;
}

extern "C" void kernel_launch(void* const* d_in, const int* in_sizes, int n_in,
                              void* d_out, int out_size, void* d_ws, size_t ws_size,
                              hipStream_t stream) {
    const float* kscores = (const float*)d_in[0];
    const float* kdesc   = (const float*)d_in[1];
    const float* dense   = (const float*)d_in[2];
    const float* times   = (const float*)d_in[3];
    float* out = (float*)d_out;

    f16* bhi = (f16*)d_ws;                        // 2*65536*256 f16 = 64 MB
    f16* blo = bhi + (size_t)2 * MM * KP;         // 64 MB
    f16* ahi = blo + (size_t)2 * MM * KP;         // 1 MB
    f16* alo = ahi + (size_t)2 * NN * KP;         // 1 MB
    float* inv_src  = (float*)(alo + (size_t)2 * NN * KP);  // 512 KB
    float* partials = inv_src + (size_t)2 * MM;             // 8 MB

    hipFuncSetAttribute((const void*)gemm_kernel,
                        hipFuncAttributeMaxDynamicSharedMemorySize, 131072);

    hipLaunchKernelGGL(convB_kernel,   dim3(2048), dim3(256), 0, stream, dense, bhi, blo, inv_src);
    hipLaunchKernelGGL(convA_kernel,   dim3(8),    dim3(256), 0, stream, kdesc, ahi, alo);
    hipLaunchKernelGGL(gemm_kernel,    dim3(2048), dim3(512), 131072, stream,
                       bhi, blo, ahi, alo, inv_src, partials);
    hipLaunchKernelGGL(combine_kernel, dim3(8),    dim3(256), 0, stream, partials, kscores, times, out);
}

// Round 4
// 224.049 us; speedup vs baseline: 4.7161x; 2.9934x over previous
//
#include <hip/hip_runtime.h>
#include <math.h>

typedef int i32x4 __attribute__((ext_vector_type(4)));
typedef int i32x16 __attribute__((ext_vector_type(16)));

#define CC 248
#define MM 65536
#define NN 1024

// ws: A_tiled [2][256 tiles][pl 2][kgrp 16][row 256][16 i8]  = 67,108,864 B
//     B_tiled [2][16 kptiles][pl 2][kgrp 16][col 64][16 i8]  =  1,048,576 B
//     partials [2][1024][64][4] float4                        =  8,388,608 B

// ---------------- convB: pixel descriptors -> i8 hi/lo planes, tiled (single pass) ----------------
__global__ __launch_bounds__(256)
void convB_kernel(const float* __restrict__ dense, char* __restrict__ Ag) {
    __shared__ char at[2][16][128][16];       // 64 KB
    __shared__ float scr[256];
    const int bid = blockIdx.x;               // 0..1023
    const int fb  = bid >> 9;                 // 0..1 -> frame 2*fb
    const int p0  = (bid & 511) * 128;
    const int tid = threadIdx.x;
    const int row  = tid & 127;
    const int half = tid >> 7;

    const float* dptr = dense + (size_t)(2 * fb) * CC * MM + (size_t)(half * 124) * MM + p0 + row;
    float v[124];
    float ss = 0.f;
#pragma unroll
    for (int i = 0; i < 124; ++i) {
        v[i] = dptr[(size_t)i * MM];
        ss += v[i] * v[i];
    }
    scr[tid] = ss;
    __syncthreads();
    float inv = 32768.0f / fmaxf(sqrtf(scr[row] + scr[128 + row]), 1e-12f);

    // zero the k-pad (c = 248..255 -> kgrp 15, bytes 8..15)
    *(long*)&at[half][15][row][8] = 0L;
#pragma unroll
    for (int i = 0; i < 124; ++i) {
        int c = half * 124 + i;
        float q = fminf(fmaxf(rintf(v[i] * inv), -32768.f), 32639.f);
        int af = (int)q;
        int a1 = (af + 128) >> 8;
        int a0 = af - (a1 << 8);
        at[0][c >> 4][row][c & 15] = (char)a1;
        at[1][c >> 4][row][c & 15] = (char)a0;
    }
    __syncthreads();

    const int tile = p0 >> 8, rhalf = (p0 >> 7) & 1;
    char* outb = Ag + ((size_t)(fb * 256 + tile)) * 131072;
#pragma unroll
    for (int it = 0; it < 16; ++it) {
        int id = tid + it * 256;              // 0..4095 16B chunks
        int pl = id >> 11, kg = (id >> 7) & 15, r2 = id & 127;
        i32x4 vv = *(const i32x4*)&at[pl][kg][r2][0];
        *(i32x4*)&outb[(size_t)pl * 65536 + kg * 4096 + (rhalf * 128 + r2) * 16] = vv;
    }
}

// ---------------- convA: keypoint descriptors -> i8 hi/lo planes, tiled ----------------
__global__ __launch_bounds__(256)
void convA_kernel(const float* __restrict__ kdesc, char* __restrict__ Bg) {
    __shared__ char bt[2][16][64][16];        // 32 KB
    __shared__ float scr[4][64];
    const int bid = blockIdx.x;               // 0..31
    const int b   = bid >> 4;
    const int kpt = bid & 15;
    const int n0  = kpt * 64;
    const int tid = threadIdx.x;
    const int col = tid & 63;
    const int q   = tid >> 6;

    const float* kp = kdesc + (size_t)(2 * b + 1) * CC * NN + n0 + col;
    float ss = 0.f;
    for (int i = 0; i < 62; ++i) {
        int c = q * 62 + i;
        float v = kp[(size_t)c * NN];
        ss += v * v;
    }
    scr[q][col] = ss;
    __syncthreads();
    float inv = 32768.0f / fmaxf(sqrtf(scr[0][col] + scr[1][col] + scr[2][col] + scr[3][col]), 1e-12f);
    if (tid < 128) {
        int c2 = tid & 63, pl = tid >> 6;
        *(long*)&bt[pl][15][c2][8] = 0L;
    }
    __syncthreads();
    for (int i = 0; i < 62; ++i) {
        int c = q * 62 + i;
        float qq = fminf(fmaxf(rintf(kp[(size_t)c * NN] * inv), -32768.f), 32639.f);
        int af = (int)qq;
        int a1 = (af + 128) >> 8;
        int a0 = af - (a1 << 8);
        bt[0][c >> 4][col][c & 15] = (char)a1;
        bt[1][c >> 4][col][c & 15] = (char)a0;
    }
    __syncthreads();
    char* outb = Bg + (size_t)(b * 16 + kpt) * 32768;
    const char* src = &bt[0][0][0][0];
#pragma unroll
    for (int it = 0; it < 8; ++it) {
        int id = tid + it * 256;              // 0..2047
        *(i32x4*)&outb[(size_t)id * 16] = *(const i32x4*)&src[(size_t)id * 16];
    }
}

// ---------------- fused i8 MFMA GEMM (exact 15-bit dot) + in-lane online softmax ----------------
// LDS: A dbuf: buf*16384 + pl*8192 + kgl*4096 + row*16    (2 bufs, 32 KB)
//      B res : 32768 + pl*16384 + kgrp*1024 + col*16      (32 KB)
__global__ __launch_bounds__(256, 2)
void gemm_kernel(const char* __restrict__ Ag, const char* __restrict__ Bg,
                 float* __restrict__ partials) {
    extern __shared__ char lds[];

    const int bid  = blockIdx.x;              // 0..2047
    const int xcd  = bid & 7;
    const int slot = bid >> 3;
    const int kpt  = slot & 15;
    const int pc8  = slot >> 4;               // 0..15
    const int pcal = xcd + 8 * pc8;           // 0..127
    const int b    = pcal >> 6;
    const int pixchunk = pcal & 63;

    const int tid  = threadIdx.x;
    const int lane = tid & 63;
    const int w    = tid >> 6;                // 0..3
    const int lrow = lane & 31;
    const int lhi  = lane >> 5;

    const char* atile0 = Ag + (size_t)(b * 256 + pixchunk * 4) * 131072;
    const char* btile  = Bg + (size_t)(b * 16 + kpt) * 32768;

    // ---- stage B (resident, 32 chunks) ----
#pragma unroll
    for (int i = 0; i < 8; ++i) {
        int c = w * 8 + i;
        int pl = c >> 4, kg = c & 15;
        const char* src = btile + pl * 16384 + kg * 1024 + lane * 16;
        __builtin_amdgcn_global_load_lds(
            (const __attribute__((address_space(1))) void*)src,
            (__attribute__((address_space(3))) void*)&lds[32768 + pl * 16384 + kg * 1024], 16, 0, 0);
    }

    auto STAGE_A = [&](int buf, int mt, int ks) {
        const char* atile = atile0 + (size_t)mt * 131072;
#pragma unroll
        for (int i = 0; i < 4; ++i) {
            int c = w * 4 + i;                 // 0..15
            int pl = c >> 3, kgl = (c >> 2) & 1, r0 = (c & 3) * 64;
            const char* src = atile + pl * 65536 + (2 * ks + kgl) * 4096 + (r0 + lane) * 16;
            __builtin_amdgcn_global_load_lds(
                (const __attribute__((address_space(1))) void*)src,
                (__attribute__((address_space(3))) void*)&lds[buf * 16384 + pl * 8192 + kgl * 4096 + r0 * 16], 16, 0, 0);
        }
    };

    i32x16 accH[2][2], accX[2][2], accL[2][2];
#pragma unroll
    for (int ap = 0; ap < 2; ++ap)
#pragma unroll
        for (int bp = 0; bp < 2; ++bp) {
            accH[ap][bp] = (i32x16)(0); accX[ap][bp] = (i32x16)(0); accL[ap][bp] = (i32x16)(0);
        }

    float rm[2], rz[2], rsu[2], rsv[2];
#pragma unroll
    for (int bp = 0; bp < 2; ++bp) { rm[bp] = -INFINITY; rz[bp] = 0.f; rsu[bp] = 0.f; rsv[bp] = 0.f; }

    STAGE_A(0, 0, 0);
    __syncthreads();

    int buf = 0;
    // score*log2(e) = (65536*H + 256*X + L) * 100*log2(e) / 2^30
    const float S2 = 100.0f * 1.4426950408889634f / 1073741824.0f;

    for (int mt = 0; mt < 4; ++mt) {
        for (int ks = 0; ks < 8; ++ks) {
            int s = mt * 8 + ks;
            if (s + 1 < 32) STAGE_A(buf ^ 1, (s + 1) >> 3, (s + 1) & 7);

            i32x4 aF[2][2], bF[2][2];
#pragma unroll
            for (int pl = 0; pl < 2; ++pl)
#pragma unroll
                for (int ap = 0; ap < 2; ++ap) {
                    int r = w * 64 + ap * 32 + lrow;
                    aF[pl][ap] = *(const i32x4*)&lds[buf * 16384 + pl * 8192 + lhi * 4096 + r * 16];
                }
#pragma unroll
            for (int pl = 0; pl < 2; ++pl)
#pragma unroll
                for (int bp = 0; bp < 2; ++bp) {
                    int kg = ks * 2 + lhi;
                    int cl = bp * 32 + lrow;
                    bF[pl][bp] = *(const i32x4*)&lds[32768 + pl * 16384 + kg * 1024 + cl * 16];
                }
#pragma unroll
            for (int ap = 0; ap < 2; ++ap)
#pragma unroll
                for (int bp = 0; bp < 2; ++bp) {
                    accH[ap][bp] = __builtin_amdgcn_mfma_i32_32x32x32_i8(aF[0][ap], bF[0][bp], accH[ap][bp], 0, 0, 0);
                    accX[ap][bp] = __builtin_amdgcn_mfma_i32_32x32x32_i8(aF[0][ap], bF[1][bp], accX[ap][bp], 0, 0, 0);
                    accX[ap][bp] = __builtin_amdgcn_mfma_i32_32x32x32_i8(aF[1][ap], bF[0][bp], accX[ap][bp], 0, 0, 0);
                    accL[ap][bp] = __builtin_amdgcn_mfma_i32_32x32x32_i8(aF[1][ap], bF[1][bp], accL[ap][bp], 0, 0, 0);
                }
            __syncthreads();
            buf ^= 1;
        }

        // ---- epilogue for m-tile mt (register-only, two-pass to limit live regs) ----
        const int mbase = pixchunk * 1024 + mt * 256 + w * 64;
#pragma unroll
        for (int bp = 0; bp < 2; ++bp) {
            float tmax = -INFINITY;
#pragma unroll
            for (int ap = 0; ap < 2; ++ap)
#pragma unroll
                for (int r = 0; r < 16; ++r) {
                    float x = ((float)accH[ap][bp][r] * 65536.f
                             + (float)accX[ap][bp][r] * 256.f
                             + (float)accL[ap][bp][r]) * S2;
                    tmax = fmaxf(tmax, x);
                }
            float tz0 = 0.f, tz1 = 0.f, tsu = 0.f;
#pragma unroll
            for (int ap = 0; ap < 2; ++ap) {
                const float ub = (float)(((mbase + ap * 32) & 255) + 4 * lhi);
#pragma unroll
                for (int r = 0; r < 16; ++r) {
                    float x = ((float)accH[ap][bp][r] * 65536.f
                             + (float)accX[ap][bp][r] * 256.f
                             + (float)accL[ap][bp][r]) * S2;
                    float e = exp2f(x - tmax);
                    if (ap == 0) tz0 += e; else tz1 += e;
                    tsu += e * (ub + (float)((r & 3) + 8 * (r >> 2)));
                }
            }
            float tzz = tz0 + tz1;
            float v0 = (float)((mbase) >> 8), v1 = (float)((mbase + 32) >> 8);
            float tsv = v0 * tz0 + v1 * tz1;
            float nm = fmaxf(rm[bp], tmax);
            float f1 = exp2f(rm[bp] - nm), f2 = exp2f(tmax - nm);
            rz[bp]  = rz[bp]  * f1 + tzz * f2;
            rsu[bp] = rsu[bp] * f1 + tsu * f2;
            rsv[bp] = rsv[bp] * f1 + tsv * f2;
            rm[bp]  = nm;
#pragma unroll
            for (int ap = 0; ap < 2; ++ap) {
                accH[ap][bp] = (i32x16)(0); accX[ap][bp] = (i32x16)(0); accL[ap][bp] = (i32x16)(0);
            }
        }
    }

    // ---- merge lane <-> lane+32, write partials ----
#pragma unroll
    for (int bp = 0; bp < 2; ++bp) {
        float m2  = __shfl_xor(rm[bp], 32, 64);
        float z2  = __shfl_xor(rz[bp], 32, 64);
        float su2 = __shfl_xor(rsu[bp], 32, 64);
        float sv2 = __shfl_xor(rsv[bp], 32, 64);
        float nm = fmaxf(rm[bp], m2);
        float f1 = exp2f(rm[bp] - nm), f2 = exp2f(m2 - nm);
        rz[bp]  = rz[bp]  * f1 + z2  * f2;
        rsu[bp] = rsu[bp] * f1 + su2 * f2;
        rsv[bp] = rsv[bp] * f1 + sv2 * f2;
        rm[bp]  = nm;
    }
    if (lane < 32) {
#pragma unroll
        for (int bp = 0; bp < 2; ++bp) {
            int n = kpt * 64 + bp * 32 + lane;
            size_t idx = (((size_t)b * NN + n) * 64 + pixchunk) * 4 + w;
            ((float4*)partials)[idx] = make_float4(rm[bp], rz[bp], rsu[bp], rsv[bp]);
        }
    }
}

// ---------------- combine: one wave per (b,n) row ----------------
__global__ __launch_bounds__(256)
void combine_kernel(const float* __restrict__ partials,
                    const float* __restrict__ kscores,
                    const float* __restrict__ times,
                    float* __restrict__ out) {
    const int wg   = blockIdx.x * 4 + (threadIdx.x >> 6);  // 0..2047 = (b, n)
    const int lane = threadIdx.x & 63;
    const int b = wg >> 10, n = wg & 1023;
    const float4* pp = (const float4*)partials + (size_t)wg * 256;

    float m = -INFINITY, z = 0.f, su = 0.f, sv = 0.f;
#pragma unroll
    for (int i = 0; i < 4; ++i) {
        float4 p = pp[i * 64 + lane];
        float nm = fmaxf(m, p.x);
        float f1 = exp2f(m - nm), f2 = exp2f(p.x - nm);
        z = z * f1 + p.y * f2; su = su * f1 + p.z * f2; sv = sv * f1 + p.w * f2; m = nm;
    }
#pragma unroll
    for (int mask = 32; mask >= 1; mask >>= 1) {
        float m2  = __shfl_xor(m, mask, 64);
        float z2  = __shfl_xor(z, mask, 64);
        float su2 = __shfl_xor(su, mask, 64);
        float sv2 = __shfl_xor(sv, mask, 64);
        float nm = fmaxf(m, m2);
        float f1 = exp2f(m - nm), f2 = exp2f(m2 - nm);
        z = z * f1 + z2 * f2; su = su * f1 + su2 * f2; sv = sv * f1 + sv2 * f2; m = nm;
    }

    if (lane == 0) {
        float u = su / z, v = sv / z;
        out[(size_t)wg * 2 + 0] = u;
        out[(size_t)wg * 2 + 1] = v;
        out[4096 + wg] = kscores[(size_t)(2 * b + 1) * NN + n];
        if (wg == 0) { out[6144] = 1.0f; out[6145] = 3.0f; }

        const float* timg = times + (size_t)(2 * b) * MM;
        float u0 = fminf(fmaxf(floorf(u), 0.f), 255.f);
        float v0 = fminf(fmaxf(floorf(v), 0.f), 255.f);
        float u1 = fminf(u0 + 1.f, 255.f);
        float v1 = fminf(v0 + 1.f, 255.f);
        float au = u - u0, av = v - v0;
        int u0i = (int)u0, u1i = (int)u1, v0i = (int)v0, v1i = (int)v1;
        float t00 = timg[v0i * 256 + u0i], t01 = timg[v0i * 256 + u1i];
        float t10 = timg[v1i * 256 + u0i], t11 = timg[v1i * 256 + u1i];
        float t = t00 * (1.f - au) * (1.f - av) + t01 * au * (1.f - av)
                + t10 * (1.f - au) * av + t11 * au * av;
        out[6146 + wg] = t;
    }
}

extern "C" void kernel_launch(void* const* d_in, const int* in_sizes, int n_in,
                              void* d_out, int out_size, void* d_ws, size_t ws_size,
                              hipStream_t stream) {
    const float* kscores = (const float*)d_in[0];
    const float* kdesc   = (const float*)d_in[1];
    const float* dense   = (const float*)d_in[2];
    const float* times   = (const float*)d_in[3];
    float* out = (float*)d_out;

    char* Ag = (char*)d_ws;                                   // 67,108,864 B
    char* Bg = Ag + (size_t)2 * 256 * 131072;                 //  1,048,576 B
    float* partials = (float*)(Bg + (size_t)2 * 16 * 32768);  //  8,388,608 B

    hipFuncSetAttribute((const void*)gemm_kernel,
                        hipFuncAttributeMaxDynamicSharedMemorySize, 65536);

    hipLaunchKernelGGL(convB_kernel,   dim3(1024), dim3(256), 0, stream, dense, Ag);
    hipLaunchKernelGGL(convA_kernel,   dim3(32),   dim3(256), 0, stream, kdesc, Bg);
    hipLaunchKernelGGL(gemm_kernel,    dim3(2048), dim3(256), 65536, stream, Ag, Bg, partials);
    hipLaunchKernelGGL(combine_kernel, dim3(512),  dim3(256), 0, stream, partials, kscores, times, out);
}

// Round 5
// 219.836 us; speedup vs baseline: 4.8065x; 1.0192x over previous
//
#include <hip/hip_runtime.h>
#include <math.h>

typedef int i32x4 __attribute__((ext_vector_type(4)));
typedef int i32x16 __attribute__((ext_vector_type(16)));

#define CC 248
#define MM 65536
#define NN 1024

// ws: A_tiled [2][256 tiles][pl 2][kgrp 16][row 256][16 i8]  = 67,108,864 B
//     B_tiled [2][16 kptiles][pl 2][kgrp 16][col 64][16 i8]  =  1,048,576 B
//     partials [2][1024][64][4] float4                        =  8,388,608 B

// ---------------- convB: pixel descriptors -> i8 hi/lo planes, tiled (single pass) ----------------
__global__ __launch_bounds__(256)
void convB_kernel(const float* __restrict__ dense, char* __restrict__ Ag) {
    __shared__ char at[2][16][128][16];       // 64 KB
    __shared__ float scr[256];
    const int bid = blockIdx.x;               // 0..1023
    const int fb  = bid >> 9;                 // 0..1 -> frame 2*fb
    const int p0  = (bid & 511) * 128;
    const int tid = threadIdx.x;
    const int row  = tid & 127;
    const int half = tid >> 7;

    const float* dptr = dense + (size_t)(2 * fb) * CC * MM + (size_t)(half * 124) * MM + p0 + row;
    float v[124];
    float ss = 0.f;
#pragma unroll
    for (int i = 0; i < 124; ++i) {
        v[i] = dptr[(size_t)i * MM];
        ss += v[i] * v[i];
    }
    scr[tid] = ss;
    __syncthreads();
    float inv = 32768.0f / fmaxf(sqrtf(scr[row] + scr[128 + row]), 1e-12f);

    // zero the k-pad (c = 248..255 -> kgrp 15, bytes 8..15)
    *(long*)&at[half][15][row][8] = 0L;
#pragma unroll
    for (int i = 0; i < 124; ++i) {
        int c = half * 124 + i;
        float q = fminf(fmaxf(rintf(v[i] * inv), -32768.f), 32639.f);
        int af = (int)q;
        int a1 = (af + 128) >> 8;
        int a0 = af - (a1 << 8);
        at[0][c >> 4][row][c & 15] = (char)a1;
        at[1][c >> 4][row][c & 15] = (char)a0;
    }
    __syncthreads();

    const int tile = p0 >> 8, rhalf = (p0 >> 7) & 1;
    char* outb = Ag + ((size_t)(fb * 256 + tile)) * 131072;
#pragma unroll
    for (int it = 0; it < 16; ++it) {
        int id = tid + it * 256;              // 0..4095 16B chunks
        int pl = id >> 11, kg = (id >> 7) & 15, r2 = id & 127;
        i32x4 vv = *(const i32x4*)&at[pl][kg][r2][0];
        *(i32x4*)&outb[(size_t)pl * 65536 + kg * 4096 + (rhalf * 128 + r2) * 16] = vv;
    }
}

// ---------------- convA: keypoint descriptors -> i8 hi/lo planes, tiled ----------------
__global__ __launch_bounds__(256)
void convA_kernel(const float* __restrict__ kdesc, char* __restrict__ Bg) {
    __shared__ char bt[2][16][64][16];        // 32 KB
    __shared__ float scr[4][64];
    const int bid = blockIdx.x;               // 0..31
    const int b   = bid >> 4;
    const int kpt = bid & 15;
    const int n0  = kpt * 64;
    const int tid = threadIdx.x;
    const int col = tid & 63;
    const int q   = tid >> 6;

    const float* kp = kdesc + (size_t)(2 * b + 1) * CC * NN + n0 + col;
    float ss = 0.f;
    for (int i = 0; i < 62; ++i) {
        int c = q * 62 + i;
        float v = kp[(size_t)c * NN];
        ss += v * v;
    }
    scr[q][col] = ss;
    __syncthreads();
    float inv = 32768.0f / fmaxf(sqrtf(scr[0][col] + scr[1][col] + scr[2][col] + scr[3][col]), 1e-12f);
    if (tid < 128) {
        int c2 = tid & 63, pl = tid >> 6;
        *(long*)&bt[pl][15][c2][8] = 0L;
    }
    __syncthreads();
    for (int i = 0; i < 62; ++i) {
        int c = q * 62 + i;
        float qq = fminf(fmaxf(rintf(kp[(size_t)c * NN] * inv), -32768.f), 32639.f);
        int af = (int)qq;
        int a1 = (af + 128) >> 8;
        int a0 = af - (a1 << 8);
        bt[0][c >> 4][col][c & 15] = (char)a1;
        bt[1][c >> 4][col][c & 15] = (char)a0;
    }
    __syncthreads();
    char* outb = Bg + (size_t)(b * 16 + kpt) * 32768;
    const char* src = &bt[0][0][0][0];
#pragma unroll
    for (int it = 0; it < 8; ++it) {
        int id = tid + it * 256;              // 0..2047
        *(i32x4*)&outb[(size_t)id * 16] = *(const i32x4*)&src[(size_t)id * 16];
    }
}

// ---------------- fused i8 MFMA GEMM, barrier-free per-wave pipeline ----------------
// LDS: A per-wave dbuf: buf*16384 + w*4096 + pl*2048 + kgl*1024 + r*16   (32 KB)
//      B resident      : 32768 + pl*16384 + kgrp*1024 + col*16           (32 KB)
__global__ __launch_bounds__(256, 2)
void gemm_kernel(const char* __restrict__ Ag, const char* __restrict__ Bg,
                 float* __restrict__ partials) {
    extern __shared__ char lds[];

    const int bid  = blockIdx.x;              // 0..2047
    const int xcd  = bid & 7;
    const int slot = bid >> 3;
    const int kpt  = slot & 15;
    const int pc8  = slot >> 4;               // 0..15
    const int pcal = xcd + 8 * pc8;           // 0..127
    const int b    = pcal >> 6;
    const int pixchunk = pcal & 63;

    const int tid  = threadIdx.x;
    const int lane = tid & 63;
    const int w    = tid >> 6;                // 0..3
    const int lrow = lane & 31;
    const int lhi  = lane >> 5;

    const char* atile0 = Ag + (size_t)(b * 256 + pixchunk * 4) * 131072;
    const char* btile  = Bg + (size_t)(b * 16 + kpt) * 32768;

    // ---- stage B (resident, 32 chunks, cooperative) ----
#pragma unroll
    for (int i = 0; i < 8; ++i) {
        int c = w * 8 + i;
        int pl = c >> 4, kg = c & 15;
        const char* src = btile + pl * 16384 + kg * 1024 + lane * 16;
        __builtin_amdgcn_global_load_lds(
            (const __attribute__((address_space(1))) void*)src,
            (__attribute__((address_space(3))) void*)&lds[32768 + pl * 16384 + kg * 1024], 16, 0, 0);
    }

    // per-wave A staging: wave w owns rows w*64..w*64+63 of each slice
    auto STAGE_A = [&](int buf, int s) {
        const int mt = s >> 3, ks = s & 7;
        const char* atile = atile0 + (size_t)mt * 131072;
#pragma unroll
        for (int pl = 0; pl < 2; ++pl)
#pragma unroll
            for (int kgl = 0; kgl < 2; ++kgl) {
                const char* src = atile + pl * 65536 + (2 * ks + kgl) * 4096 + (w * 64 + lane) * 16;
                char* dst = &lds[buf * 16384 + w * 4096 + pl * 2048 + kgl * 1024];
                __builtin_amdgcn_global_load_lds(
                    (const __attribute__((address_space(1))) void*)src,
                    (__attribute__((address_space(3))) void*)dst, 16, 0, 0);
            }
    };

    i32x16 accH[2][2], accX[2][2], accL[2][2];
#pragma unroll
    for (int ap = 0; ap < 2; ++ap)
#pragma unroll
        for (int bp = 0; bp < 2; ++bp) {
            accH[ap][bp] = (i32x16)(0); accX[ap][bp] = (i32x16)(0); accL[ap][bp] = (i32x16)(0);
        }

    float rm[2], rz[2], rsu[2], rsv[2];
#pragma unroll
    for (int bp = 0; bp < 2; ++bp) { rm[bp] = -INFINITY; rz[bp] = 0.f; rsu[bp] = 0.f; rsv[bp] = 0.f; }

    STAGE_A(0, 0);
    __syncthreads();                           // one-time: B + A(0) visible

    int buf = 0;
    // score*log2(e) = (65536*H + 256*X + L) * 100*log2(e) / 2^30
    const float S2 = 100.0f * 1.4426950408889634f / 1073741824.0f;
    const float cH = 65536.0f * S2;

    for (int mt = 0; mt < 4; ++mt) {
        for (int ks = 0; ks < 8; ++ks) {
            const int s = mt * 8 + ks;
            if (s < 31) {
                STAGE_A(buf ^ 1, s + 1);
                asm volatile("s_waitcnt vmcnt(4)" ::: "memory");   // slice-s loads drained
            } else {
                asm volatile("s_waitcnt vmcnt(0)" ::: "memory");
            }

            i32x4 aF[2][2], bF[2][2];
#pragma unroll
            for (int pl = 0; pl < 2; ++pl)
#pragma unroll
                for (int ap = 0; ap < 2; ++ap) {
                    int rr = ap * 32 + lrow;
                    aF[pl][ap] = *(const i32x4*)&lds[buf * 16384 + w * 4096 + pl * 2048 + lhi * 1024 + rr * 16];
                }
#pragma unroll
            for (int pl = 0; pl < 2; ++pl)
#pragma unroll
                for (int bp = 0; bp < 2; ++bp) {
                    int kg = ks * 2 + lhi;
                    int cl = bp * 32 + lrow;
                    bF[pl][bp] = *(const i32x4*)&lds[32768 + pl * 16384 + kg * 1024 + cl * 16];
                }
            __builtin_amdgcn_s_setprio(1);
#pragma unroll
            for (int ap = 0; ap < 2; ++ap)
#pragma unroll
                for (int bp = 0; bp < 2; ++bp) {
                    accH[ap][bp] = __builtin_amdgcn_mfma_i32_32x32x32_i8(aF[0][ap], bF[0][bp], accH[ap][bp], 0, 0, 0);
                    accX[ap][bp] = __builtin_amdgcn_mfma_i32_32x32x32_i8(aF[0][ap], bF[1][bp], accX[ap][bp], 0, 0, 0);
                    accX[ap][bp] = __builtin_amdgcn_mfma_i32_32x32x32_i8(aF[1][ap], bF[0][bp], accX[ap][bp], 0, 0, 0);
                    accL[ap][bp] = __builtin_amdgcn_mfma_i32_32x32x32_i8(aF[1][ap], bF[1][bp], accL[ap][bp], 0, 0, 0);
                }
            __builtin_amdgcn_s_setprio(0);
            buf ^= 1;
        }

        // ---- epilogue for m-tile mt (int-max base, single combine pass) ----
        const int mbase = pixchunk * 1024 + mt * 256 + w * 64;
#pragma unroll
        for (int bp = 0; bp < 2; ++bp) {
            int hm = accH[0][bp][0];
#pragma unroll
            for (int ap = 0; ap < 2; ++ap)
#pragma unroll
                for (int r = 0; r < 16; ++r) {
                    int h = accH[ap][bp][r];
                    hm = (h > hm) ? h : hm;
                }
            const float bx = (float)hm * cH;   // base (<= true max + eps; exactness not required)
            float tz0 = 0.f, tz1 = 0.f, tsu = 0.f;
#pragma unroll
            for (int ap = 0; ap < 2; ++ap) {
                const float ub = (float)(((mbase + ap * 32) & 255) + 4 * lhi);
#pragma unroll
                for (int r = 0; r < 16; ++r) {
                    int dH = accH[ap][bp][r] - hm;
                    int XL = (accX[ap][bp][r] << 8) + accL[ap][bp][r];
                    float e = exp2f(fmaf((float)dH, cH, (float)XL * S2));
                    if (ap == 0) tz0 += e; else tz1 += e;
                    tsu += e * (ub + (float)((r & 3) + 8 * (r >> 2)));
                }
            }
            float tzz = tz0 + tz1;
            float v0 = (float)((mbase) >> 8), v1 = (float)((mbase + 32) >> 8);
            float tsv = v0 * tz0 + v1 * tz1;
            float nm = fmaxf(rm[bp], bx);
            float f1 = exp2f(rm[bp] - nm), f2 = exp2f(bx - nm);
            rz[bp]  = rz[bp]  * f1 + tzz * f2;
            rsu[bp] = rsu[bp] * f1 + tsu * f2;
            rsv[bp] = rsv[bp] * f1 + tsv * f2;
            rm[bp]  = nm;
#pragma unroll
            for (int ap = 0; ap < 2; ++ap) {
                accH[ap][bp] = (i32x16)(0); accX[ap][bp] = (i32x16)(0); accL[ap][bp] = (i32x16)(0);
            }
        }
    }

    // ---- merge lane <-> lane+32, write partials ----
#pragma unroll
    for (int bp = 0; bp < 2; ++bp) {
        float m2  = __shfl_xor(rm[bp], 32, 64);
        float z2  = __shfl_xor(rz[bp], 32, 64);
        float su2 = __shfl_xor(rsu[bp], 32, 64);
        float sv2 = __shfl_xor(rsv[bp], 32, 64);
        float nm = fmaxf(rm[bp], m2);
        float f1 = exp2f(rm[bp] - nm), f2 = exp2f(m2 - nm);
        rz[bp]  = rz[bp]  * f1 + z2  * f2;
        rsu[bp] = rsu[bp] * f1 + su2 * f2;
        rsv[bp] = rsv[bp] * f1 + sv2 * f2;
        rm[bp]  = nm;
    }
    if (lane < 32) {
#pragma unroll
        for (int bp = 0; bp < 2; ++bp) {
            int n = kpt * 64 + bp * 32 + lane;
            size_t idx = (((size_t)b * NN + n) * 64 + pixchunk) * 4 + w;
            ((float4*)partials)[idx] = make_float4(rm[bp], rz[bp], rsu[bp], rsv[bp]);
        }
    }
}

// ---------------- combine: one wave per (b,n) row ----------------
__global__ __launch_bounds__(256)
void combine_kernel(const float* __restrict__ partials,
                    const float* __restrict__ kscores,
                    const float* __restrict__ times,
                    float* __restrict__ out) {
    const int wg   = blockIdx.x * 4 + (threadIdx.x >> 6);  // 0..2047 = (b, n)
    const int lane = threadIdx.x & 63;
    const int b = wg >> 10, n = wg & 1023;
    const float4* pp = (const float4*)partials + (size_t)wg * 256;

    float m = -INFINITY, z = 0.f, su = 0.f, sv = 0.f;
#pragma unroll
    for (int i = 0; i < 4; ++i) {
        float4 p = pp[i * 64 + lane];
        float nm = fmaxf(m, p.x);
        float f1 = exp2f(m - nm), f2 = exp2f(p.x - nm);
        z = z * f1 + p.y * f2; su = su * f1 + p.z * f2; sv = sv * f1 + p.w * f2; m = nm;
    }
#pragma unroll
    for (int mask = 32; mask >= 1; mask >>= 1) {
        float m2  = __shfl_xor(m, mask, 64);
        float z2  = __shfl_xor(z, mask, 64);
        float su2 = __shfl_xor(su, mask, 64);
        float sv2 = __shfl_xor(sv, mask, 64);
        float nm = fmaxf(m, m2);
        float f1 = exp2f(m - nm), f2 = exp2f(m2 - nm);
        z = z * f1 + z2 * f2; su = su * f1 + su2 * f2; sv = sv * f1 + sv2 * f2; m = nm;
    }

    if (lane == 0) {
        float u = su / z, v = sv / z;
        out[(size_t)wg * 2 + 0] = u;
        out[(size_t)wg * 2 + 1] = v;
        out[4096 + wg] = kscores[(size_t)(2 * b + 1) * NN + n];
        if (wg == 0) { out[6144] = 1.0f; out[6145] = 3.0f; }

        const float* timg = times + (size_t)(2 * b) * MM;
        float u0 = fminf(fmaxf(floorf(u), 0.f), 255.f);
        float v0 = fminf(fmaxf(floorf(v), 0.f), 255.f);
        float u1 = fminf(u0 + 1.f, 255.f);
        float v1 = fminf(v0 + 1.f, 255.f);
        float au = u - u0, av = v - v0;
        int u0i = (int)u0, u1i = (int)u1, v0i = (int)v0, v1i = (int)v1;
        float t00 = timg[v0i * 256 + u0i], t01 = timg[v0i * 256 + u1i];
        float t10 = timg[v1i * 256 + u0i], t11 = timg[v1i * 256 + u1i];
        float t = t00 * (1.f - au) * (1.f - av) + t01 * au * (1.f - av)
                + t10 * (1.f - au) * av + t11 * au * av;
        out[6146 + wg] = t;
    }
}

extern "C" void kernel_launch(void* const* d_in, const int* in_sizes, int n_in,
                              void* d_out, int out_size, void* d_ws, size_t ws_size,
                              hipStream_t stream) {
    const float* kscores = (const float*)d_in[0];
    const float* kdesc   = (const float*)d_in[1];
    const float* dense   = (const float*)d_in[2];
    const float* times   = (const float*)d_in[3];
    float* out = (float*)d_out;

    char* Ag = (char*)d_ws;                                   // 67,108,864 B
    char* Bg = Ag + (size_t)2 * 256 * 131072;                 //  1,048,576 B
    float* partials = (float*)(Bg + (size_t)2 * 16 * 32768);  //  8,388,608 B

    hipFuncSetAttribute((const void*)gemm_kernel,
                        hipFuncAttributeMaxDynamicSharedMemorySize, 65536);

    hipLaunchKernelGGL(convB_kernel,   dim3(1024), dim3(256), 0, stream, dense, Ag);
    hipLaunchKernelGGL(convA_kernel,   dim3(32),   dim3(256), 0, stream, kdesc, Bg);
    hipLaunchKernelGGL(gemm_kernel,    dim3(2048), dim3(256), 65536, stream, Ag, Bg, partials);
    hipLaunchKernelGGL(combine_kernel, dim3(512),  dim3(256), 0, stream, partials, kscores, times, out);
}

// Round 6
// 183.213 us; speedup vs baseline: 5.7673x; 1.1999x over previous
//
#include <hip/hip_runtime.h>
#include <math.h>

typedef int i32x4 __attribute__((ext_vector_type(4)));
typedef int i32x16 __attribute__((ext_vector_type(16)));

#define CC 248
#define MM 65536
#define NN 1024

// ws: A_tiled [2][256 tiles][pl 2][kgrp 16][row 256][16 i8]  = 67,108,864 B
//     B_tiled [2][16 kptiles][pl 2][kgrp 16][col 64][16 i8]  =  1,048,576 B
//     partials [2][1024][64][4] float4                        =  8,388,608 B

// ---------------- convB: pixel descriptors -> i8 hi/lo planes, tiled ----------------
// 512 thr: 4 threads per pixel (64 channels each) -> 64-reg value array, dword-packed LDS writes
__global__ __launch_bounds__(512)
void convB_kernel(const float* __restrict__ dense, char* __restrict__ Ag) {
    __shared__ char at[2][16][128][16];       // 64 KB
    __shared__ float scr[4][128];
    const int bid = blockIdx.x;               // 0..1023
    const int fb  = bid >> 9;                 // 0..1 -> frame 2*fb
    const int p0  = (bid & 511) * 128;
    const int tid = threadIdx.x;
    const int row = tid & 127;
    const int q   = tid >> 7;                 // 0..3 -> channels q*64..q*64+63

    const float* dptr = dense + (size_t)(2 * fb) * CC * MM + p0 + row;
    float v[64];
    float ss = 0.f;
#pragma unroll
    for (int i = 0; i < 64; ++i) {
        int c = q * 64 + i;
        float x = (c < CC) ? dptr[(size_t)c * MM] : 0.f;
        v[i] = x;
        ss += x * x;
    }
    scr[q][row] = ss;
    __syncthreads();
    float inv = 32768.0f / fmaxf(sqrtf(scr[0][row] + scr[1][row] + scr[2][row] + scr[3][row]), 1e-12f);

#pragma unroll
    for (int j = 0; j < 16; ++j) {
        unsigned w1 = 0, w0 = 0;
#pragma unroll
        for (int t = 0; t < 4; ++t) {
            float qv = fminf(fmaxf(rintf(v[j * 4 + t] * inv), -32768.f), 32639.f);
            int af = (int)qv;
            int a1 = (af + 128) >> 8;
            int a0 = af - (a1 << 8);
            w1 |= (unsigned)(a1 & 255) << (8 * t);
            w0 |= (unsigned)(a0 & 255) << (8 * t);
        }
        int c0 = q * 64 + j * 4;
        int kg = c0 >> 4, dw = (c0 >> 2) & 3;
        *(unsigned*)&at[0][kg][row][dw * 4] = w1;
        *(unsigned*)&at[1][kg][row][dw * 4] = w0;
    }
    __syncthreads();

    const int tile = p0 >> 8, rhalf = (p0 >> 7) & 1;
    char* outb = Ag + (size_t)(fb * 256 + tile) * 131072;
#pragma unroll
    for (int it = 0; it < 8; ++it) {
        int id = tid + it * 512;              // 0..4095 16B chunks
        int pl = id >> 11, kg = (id >> 7) & 15, r2 = id & 127;
        i32x4 vv = *(const i32x4*)&at[pl][kg][r2][0];
        *(i32x4*)&outb[(size_t)pl * 65536 + kg * 4096 + (rhalf * 128 + r2) * 16] = vv;
    }
}

// ---------------- convA: keypoint descriptors -> i8 hi/lo planes, tiled ----------------
__global__ __launch_bounds__(256)
void convA_kernel(const float* __restrict__ kdesc, char* __restrict__ Bg) {
    __shared__ char bt[2][16][64][16];        // 32 KB
    __shared__ float scr[4][64];
    const int bid = blockIdx.x;               // 0..31
    const int b   = bid >> 4;
    const int kpt = bid & 15;
    const int n0  = kpt * 64;
    const int tid = threadIdx.x;
    const int col = tid & 63;
    const int q   = tid >> 6;

    const float* kp = kdesc + (size_t)(2 * b + 1) * CC * NN + n0 + col;
    float ss = 0.f;
    for (int i = 0; i < 62; ++i) {
        int c = q * 62 + i;
        float v = kp[(size_t)c * NN];
        ss += v * v;
    }
    scr[q][col] = ss;
    __syncthreads();
    float inv = 32768.0f / fmaxf(sqrtf(scr[0][col] + scr[1][col] + scr[2][col] + scr[3][col]), 1e-12f);
    if (tid < 128) {
        int c2 = tid & 63, pl = tid >> 6;
        *(long*)&bt[pl][15][c2][8] = 0L;
    }
    __syncthreads();
    for (int i = 0; i < 62; ++i) {
        int c = q * 62 + i;
        float qq = fminf(fmaxf(rintf(kp[(size_t)c * NN] * inv), -32768.f), 32639.f);
        int af = (int)qq;
        int a1 = (af + 128) >> 8;
        int a0 = af - (a1 << 8);
        bt[0][c >> 4][col][c & 15] = (char)a1;
        bt[1][c >> 4][col][c & 15] = (char)a0;
    }
    __syncthreads();
    char* outb = Bg + (size_t)(b * 16 + kpt) * 32768;
    const char* src = &bt[0][0][0][0];
#pragma unroll
    for (int it = 0; it < 8; ++it) {
        int id = tid + it * 256;              // 0..2047
        *(i32x4*)&outb[(size_t)id * 16] = *(const i32x4*)&src[(size_t)id * 16];
    }
}

// ---------------- fused i8 MFMA GEMM (H + X terms), barrier-free per-wave pipeline ----------------
// LDS: A per-wave dbuf: buf*16384 + w*4096 + pl*2048 + kgl*1024 + r*16   (32 KB)
//      B resident      : 32768 + pl*16384 + kgrp*1024 + col*16           (32 KB)
__global__ __launch_bounds__(256, 2)
void gemm_kernel(const char* __restrict__ Ag, const char* __restrict__ Bg,
                 float* __restrict__ partials) {
    extern __shared__ char lds[];

    const int bid  = blockIdx.x;              // 0..2047
    const int xcd  = bid & 7;
    const int slot = bid >> 3;
    const int kpt  = slot & 15;
    const int pc8  = slot >> 4;               // 0..15
    const int pcal = xcd + 8 * pc8;           // 0..127
    const int b    = pcal >> 6;
    const int pixchunk = pcal & 63;

    const int tid  = threadIdx.x;
    const int lane = tid & 63;
    const int w    = tid >> 6;                // 0..3
    const int lrow = lane & 31;
    const int lhi  = lane >> 5;

    const char* atile0 = Ag + (size_t)(b * 256 + pixchunk * 4) * 131072;
    const char* btile  = Bg + (size_t)(b * 16 + kpt) * 32768;

    // ---- stage B (resident, 32 chunks, cooperative) ----
#pragma unroll
    for (int i = 0; i < 8; ++i) {
        int c = w * 8 + i;
        int pl = c >> 4, kg = c & 15;
        const char* src = btile + pl * 16384 + kg * 1024 + lane * 16;
        __builtin_amdgcn_global_load_lds(
            (const __attribute__((address_space(1))) void*)src,
            (__attribute__((address_space(3))) void*)&lds[32768 + pl * 16384 + kg * 1024], 16, 0, 0);
    }

    // per-wave A staging: wave w owns rows w*64..w*64+63 of each slice
    auto STAGE_A = [&](int buf, int mtn, int ksn) {
        const char* atile = atile0 + (size_t)mtn * 131072;
#pragma unroll
        for (int pl = 0; pl < 2; ++pl)
#pragma unroll
            for (int kgl = 0; kgl < 2; ++kgl) {
                const char* src = atile + pl * 65536 + (2 * ksn + kgl) * 4096 + (w * 64 + lane) * 16;
                char* dst = &lds[buf * 16384 + w * 4096 + pl * 2048 + kgl * 1024];
                __builtin_amdgcn_global_load_lds(
                    (const __attribute__((address_space(1))) void*)src,
                    (__attribute__((address_space(3))) void*)dst, 16, 0, 0);
            }
    };

    i32x16 accH[2][2], accX[2][2];
#pragma unroll
    for (int ap = 0; ap < 2; ++ap)
#pragma unroll
        for (int bp = 0; bp < 2; ++bp) { accH[ap][bp] = (i32x16)(0); accX[ap][bp] = (i32x16)(0); }

    float rm[2], rz[2], rsu[2], rsv[2];
#pragma unroll
    for (int bp = 0; bp < 2; ++bp) { rm[bp] = -INFINITY; rz[bp] = 0.f; rsu[bp] = 0.f; rsv[bp] = 0.f; }

    STAGE_A(0, 0, 0);
    __syncthreads();                           // one-time: B + A(0) visible

    // score*log2(e) = (65536*H + 256*X) * 100*log2(e) / 2^30
    const float S2 = 100.0f * 1.4426950408889634f / 1073741824.0f;
    const float cH = 65536.0f * S2;
    const float cX = 256.0f * S2;

    for (int mt = 0; mt < 4; ++mt) {
#pragma unroll
        for (int ks = 0; ks < 8; ++ks) {
            if (mt * 8 + ks < 31) {
                STAGE_A((ks + 1) & 1, (ks == 7) ? mt + 1 : mt, (ks == 7) ? 0 : ks + 1);
                asm volatile("s_waitcnt vmcnt(4)" ::: "memory");   // this slice's loads drained
            } else {
                asm volatile("s_waitcnt vmcnt(0)" ::: "memory");
            }
            const int buf = ks & 1;

            i32x4 aF[2][2], bF[2][2];
#pragma unroll
            for (int pl = 0; pl < 2; ++pl)
#pragma unroll
                for (int ap = 0; ap < 2; ++ap) {
                    int rr = ap * 32 + lrow;
                    aF[pl][ap] = *(const i32x4*)&lds[buf * 16384 + w * 4096 + pl * 2048 + lhi * 1024 + rr * 16];
                }
#pragma unroll
            for (int pl = 0; pl < 2; ++pl)
#pragma unroll
                for (int bp = 0; bp < 2; ++bp) {
                    int kg = ks * 2 + lhi;
                    int cl = bp * 32 + lrow;
                    bF[pl][bp] = *(const i32x4*)&lds[32768 + pl * 16384 + kg * 1024 + cl * 16];
                }
            __builtin_amdgcn_s_setprio(1);
#pragma unroll
            for (int ap = 0; ap < 2; ++ap)
#pragma unroll
                for (int bp = 0; bp < 2; ++bp) {
                    accH[ap][bp] = __builtin_amdgcn_mfma_i32_32x32x32_i8(aF[0][ap], bF[0][bp], accH[ap][bp], 0, 0, 0);
                    accX[ap][bp] = __builtin_amdgcn_mfma_i32_32x32x32_i8(aF[0][ap], bF[1][bp], accX[ap][bp], 0, 0, 0);
                    accX[ap][bp] = __builtin_amdgcn_mfma_i32_32x32x32_i8(aF[1][ap], bF[0][bp], accX[ap][bp], 0, 0, 0);
                }
            __builtin_amdgcn_s_setprio(0);
        }

        // ---- epilogue for m-tile mt ----
        const int mbase = pixchunk * 1024 + mt * 256 + w * 64;
        const float vcoord = (float)(mbase >> 8);   // constant across the tile
#pragma unroll
        for (int bp = 0; bp < 2; ++bp) {
            // pass 1: integer max over H
            int hm = accH[0][bp][0];
#pragma unroll
            for (int ap = 0; ap < 2; ++ap)
#pragma unroll
                for (int r = 0; r < 16; ++r) {
                    int h = accH[ap][bp][r];
                    hm = (h > hm) ? h : hm;
                }
            const float bx = (float)hm * cH;   // tile base exponent (log2 units)
            // pass 2: exp + moments. u = ub_ap + roff(r); Se*u = ub0*tz0 + ub1*tz1 + tsur
            float tz0 = 0.f, tz1 = 0.f, tsur = 0.f;
#pragma unroll
            for (int ap = 0; ap < 2; ++ap)
#pragma unroll
                for (int r = 0; r < 16; ++r) {
                    int dH = accH[ap][bp][r] - hm;                     // exact
                    float arg = fmaf((float)dH, cH, (float)accX[ap][bp][r] * cX);
                    float e = exp2f(arg);
                    if (ap == 0) tz0 += e; else tz1 += e;
                    tsur = fmaf(e, (float)((r & 3) + 8 * (r >> 2)), tsur);
                }
            const float ub0 = (float)((mbase & 255) + 4 * lhi);
            const float ub1 = ub0 + 32.0f;
            float tzz = tz0 + tz1;
            float tsu = fmaf(ub0, tz0, fmaf(ub1, tz1, tsur));
            float tsv = vcoord * tzz;
            float nm = fmaxf(rm[bp], bx);
            float f1 = exp2f(rm[bp] - nm), f2 = exp2f(bx - nm);
            rz[bp]  = rz[bp]  * f1 + tzz * f2;
            rsu[bp] = rsu[bp] * f1 + tsu * f2;
            rsv[bp] = rsv[bp] * f1 + tsv * f2;
            rm[bp]  = nm;
#pragma unroll
            for (int ap = 0; ap < 2; ++ap) { accH[ap][bp] = (i32x16)(0); accX[ap][bp] = (i32x16)(0); }
        }
    }

    // ---- merge lane <-> lane+32, write partials ----
#pragma unroll
    for (int bp = 0; bp < 2; ++bp) {
        float m2  = __shfl_xor(rm[bp], 32, 64);
        float z2  = __shfl_xor(rz[bp], 32, 64);
        float su2 = __shfl_xor(rsu[bp], 32, 64);
        float sv2 = __shfl_xor(rsv[bp], 32, 64);
        float nm = fmaxf(rm[bp], m2);
        float f1 = exp2f(rm[bp] - nm), f2 = exp2f(m2 - nm);
        rz[bp]  = rz[bp]  * f1 + z2  * f2;
        rsu[bp] = rsu[bp] * f1 + su2 * f2;
        rsv[bp] = rsv[bp] * f1 + sv2 * f2;
        rm[bp]  = nm;
    }
    if (lane < 32) {
#pragma unroll
        for (int bp = 0; bp < 2; ++bp) {
            int n = kpt * 64 + bp * 32 + lane;
            size_t idx = (((size_t)b * NN + n) * 64 + pixchunk) * 4 + w;
            ((float4*)partials)[idx] = make_float4(rm[bp], rz[bp], rsu[bp], rsv[bp]);
        }
    }
}

// ---------------- combine: one wave per (b,n) row ----------------
__global__ __launch_bounds__(256)
void combine_kernel(const float* __restrict__ partials,
                    const float* __restrict__ kscores,
                    const float* __restrict__ times,
                    float* __restrict__ out) {
    const int wg   = blockIdx.x * 4 + (threadIdx.x >> 6);  // 0..2047 = (b, n)
    const int lane = threadIdx.x & 63;
    const int b = wg >> 10, n = wg & 1023;
    const float4* pp = (const float4*)partials + (size_t)wg * 256;

    float m = -INFINITY, z = 0.f, su = 0.f, sv = 0.f;
#pragma unroll
    for (int i = 0; i < 4; ++i) {
        float4 p = pp[i * 64 + lane];
        float nm = fmaxf(m, p.x);
        float f1 = exp2f(m - nm), f2 = exp2f(p.x - nm);
        z = z * f1 + p.y * f2; su = su * f1 + p.z * f2; sv = sv * f1 + p.w * f2; m = nm;
    }
#pragma unroll
    for (int mask = 32; mask >= 1; mask >>= 1) {
        float m2  = __shfl_xor(m, mask, 64);
        float z2  = __shfl_xor(z, mask, 64);
        float su2 = __shfl_xor(su, mask, 64);
        float sv2 = __shfl_xor(sv, mask, 64);
        float nm = fmaxf(m, m2);
        float f1 = exp2f(m - nm), f2 = exp2f(m2 - nm);
        z = z * f1 + z2 * f2; su = su * f1 + su2 * f2; sv = sv * f1 + sv2 * f2; m = nm;
    }

    if (lane == 0) {
        float u = su / z, v = sv / z;
        out[(size_t)wg * 2 + 0] = u;
        out[(size_t)wg * 2 + 1] = v;
        out[4096 + wg] = kscores[(size_t)(2 * b + 1) * NN + n];
        if (wg == 0) { out[6144] = 1.0f; out[6145] = 3.0f; }

        const float* timg = times + (size_t)(2 * b) * MM;
        float u0 = fminf(fmaxf(floorf(u), 0.f), 255.f);
        float v0 = fminf(fmaxf(floorf(v), 0.f), 255.f);
        float u1 = fminf(u0 + 1.f, 255.f);
        float v1 = fminf(v0 + 1.f, 255.f);
        float au = u - u0, av = v - v0;
        int u0i = (int)u0, u1i = (int)u1, v0i = (int)v0, v1i = (int)v1;
        float t00 = timg[v0i * 256 + u0i], t01 = timg[v0i * 256 + u1i];
        float t10 = timg[v1i * 256 + u0i], t11 = timg[v1i * 256 + u1i];
        float t = t00 * (1.f - au) * (1.f - av) + t01 * au * (1.f - av)
                + t10 * (1.f - au) * av + t11 * au * av;
        out[6146 + wg] = t;
    }
}

extern "C" void kernel_launch(void* const* d_in, const int* in_sizes, int n_in,
                              void* d_out, int out_size, void* d_ws, size_t ws_size,
                              hipStream_t stream) {
    const float* kscores = (const float*)d_in[0];
    const float* kdesc   = (const float*)d_in[1];
    const float* dense   = (const float*)d_in[2];
    const float* times   = (const float*)d_in[3];
    float* out = (float*)d_out;

    char* Ag = (char*)d_ws;                                   // 67,108,864 B
    char* Bg = Ag + (size_t)2 * 256 * 131072;                 //  1,048,576 B
    float* partials = (float*)(Bg + (size_t)2 * 16 * 32768);  //  8,388,608 B

    hipFuncSetAttribute((const void*)gemm_kernel,
                        hipFuncAttributeMaxDynamicSharedMemorySize, 65536);

    hipLaunchKernelGGL(convB_kernel,   dim3(1024), dim3(512), 0, stream, dense, Ag);
    hipLaunchKernelGGL(convA_kernel,   dim3(32),   dim3(256), 0, stream, kdesc, Bg);
    hipLaunchKernelGGL(gemm_kernel,    dim3(2048), dim3(256), 65536, stream, Ag, Bg, partials);
    hipLaunchKernelGGL(combine_kernel, dim3(512),  dim3(256), 0, stream, partials, kscores, times, out);
}

// Round 7
// 167.877 us; speedup vs baseline: 6.2942x; 1.0914x over previous
//
#include <hip/hip_runtime.h>
#include <math.h>

typedef int i32x4 __attribute__((ext_vector_type(4)));
typedef int i32x16 __attribute__((ext_vector_type(16)));

#define CC 248
#define MM 65536
#define NN 1024

__device__ __forceinline__ float fexp2(float x) { return __builtin_amdgcn_exp2f(x); }

// ws: A_tiled [2][256 tiles][pl 2][kgrp 16][row 256][16 i8]  = 67,108,864 B
//     B_tiled [2][16 kptiles][pl 2][kgrp 16][col 64][16 i8]  =  1,048,576 B
//     partials [2][1024][64][4] float4                        =  8,388,608 B

// ---------------- convB: pixel descriptors -> i8 hi/lo planes, tiled ----------------
__global__ __launch_bounds__(512)
void convB_kernel(const float* __restrict__ dense, char* __restrict__ Ag) {
    __shared__ char at[2][16][128][16];       // 64 KB
    __shared__ float scr[4][128];
    const int bid = blockIdx.x;               // 0..1023
    const int fb  = bid >> 9;                 // 0..1 -> frame 2*fb
    const int p0  = (bid & 511) * 128;
    const int tid = threadIdx.x;
    const int row = tid & 127;
    const int q   = tid >> 7;                 // 0..3 -> channels q*64..q*64+63

    const float* dptr = dense + (size_t)(2 * fb) * CC * MM + p0 + row;
    float v[64];
    float ss = 0.f;
#pragma unroll
    for (int i = 0; i < 64; ++i) {
        int c = q * 64 + i;
        float x = (c < CC) ? dptr[(size_t)c * MM] : 0.f;
        v[i] = x;
        ss += x * x;
    }
    scr[q][row] = ss;
    __syncthreads();
    float inv = 32768.0f / fmaxf(sqrtf(scr[0][row] + scr[1][row] + scr[2][row] + scr[3][row]), 1e-12f);

#pragma unroll
    for (int j = 0; j < 16; ++j) {
        unsigned w1 = 0, w0 = 0;
#pragma unroll
        for (int t = 0; t < 4; ++t) {
            float qv = fminf(fmaxf(rintf(v[j * 4 + t] * inv), -32768.f), 32639.f);
            int af = (int)qv;
            int a1 = (af + 128) >> 8;
            int a0 = af - (a1 << 8);
            w1 |= (unsigned)(a1 & 255) << (8 * t);
            w0 |= (unsigned)(a0 & 255) << (8 * t);
        }
        int c0 = q * 64 + j * 4;
        int kg = c0 >> 4, dw = (c0 >> 2) & 3;
        *(unsigned*)&at[0][kg][row][dw * 4] = w1;
        *(unsigned*)&at[1][kg][row][dw * 4] = w0;
    }
    __syncthreads();

    const int tile = p0 >> 8, rhalf = (p0 >> 7) & 1;
    char* outb = Ag + (size_t)(fb * 256 + tile) * 131072;
#pragma unroll
    for (int it = 0; it < 8; ++it) {
        int id = tid + it * 512;              // 0..4095 16B chunks
        int pl = id >> 11, kg = (id >> 7) & 15, r2 = id & 127;
        i32x4 vv = *(const i32x4*)&at[pl][kg][r2][0];
        *(i32x4*)&outb[(size_t)pl * 65536 + kg * 4096 + (rhalf * 128 + r2) * 16] = vv;
    }
}

// ---------------- convA: keypoint descriptors -> i8 hi/lo planes, tiled ----------------
__global__ __launch_bounds__(256)
void convA_kernel(const float* __restrict__ kdesc, char* __restrict__ Bg) {
    __shared__ char bt[2][16][64][16];        // 32 KB
    __shared__ float scr[4][64];
    const int bid = blockIdx.x;               // 0..31
    const int b   = bid >> 4;
    const int kpt = bid & 15;
    const int n0  = kpt * 64;
    const int tid = threadIdx.x;
    const int col = tid & 63;
    const int q   = tid >> 6;

    const float* kp = kdesc + (size_t)(2 * b + 1) * CC * NN + n0 + col;
    float ss = 0.f;
    for (int i = 0; i < 62; ++i) {
        int c = q * 62 + i;
        float v = kp[(size_t)c * NN];
        ss += v * v;
    }
    scr[q][col] = ss;
    __syncthreads();
    float inv = 32768.0f / fmaxf(sqrtf(scr[0][col] + scr[1][col] + scr[2][col] + scr[3][col]), 1e-12f);
    if (tid < 128) {
        int c2 = tid & 63, pl = tid >> 6;
        *(long*)&bt[pl][15][c2][8] = 0L;
    }
    __syncthreads();
    for (int i = 0; i < 62; ++i) {
        int c = q * 62 + i;
        float qq = fminf(fmaxf(rintf(kp[(size_t)c * NN] * inv), -32768.f), 32639.f);
        int af = (int)qq;
        int a1 = (af + 128) >> 8;
        int a0 = af - (a1 << 8);
        bt[0][c >> 4][col][c & 15] = (char)a1;
        bt[1][c >> 4][col][c & 15] = (char)a0;
    }
    __syncthreads();
    char* outb = Bg + (size_t)(b * 16 + kpt) * 32768;
    const char* src = &bt[0][0][0][0];
#pragma unroll
    for (int it = 0; it < 8; ++it) {
        int id = tid + it * 256;              // 0..2047
        *(i32x4*)&outb[(size_t)id * 16] = *(const i32x4*)&src[(size_t)id * 16];
    }
}

// ---------------- fused i8 MFMA GEMM (H + X terms), barrier-free per-wave pipeline ----------------
// LDS: A per-wave dbuf: buf*16384 + w*4096 + pl*2048 + kgl*1024 + r*16   (32 KB)
//      B resident      : 32768 + pl*16384 + kgrp*1024 + col*16           (32 KB)
__global__ __launch_bounds__(256, 2)
void gemm_kernel(const char* __restrict__ Ag, const char* __restrict__ Bg,
                 float* __restrict__ partials) {
    extern __shared__ char lds[];

    const int bid  = blockIdx.x;              // 0..2047
    const int xcd  = bid & 7;
    const int slot = bid >> 3;
    const int kpt  = slot & 15;
    const int pc8  = slot >> 4;               // 0..15
    const int pcal = xcd + 8 * pc8;           // 0..127
    const int b    = pcal >> 6;
    const int pixchunk = pcal & 63;

    const int tid  = threadIdx.x;
    const int lane = tid & 63;
    const int w    = tid >> 6;                // 0..3
    const int lrow = lane & 31;
    const int lhi  = lane >> 5;

    const char* atile0 = Ag + (size_t)(b * 256 + pixchunk * 4) * 131072;
    const char* btile  = Bg + (size_t)(b * 16 + kpt) * 32768;

    // ---- stage B (resident, 32 chunks, cooperative) ----
#pragma unroll
    for (int i = 0; i < 8; ++i) {
        int c = w * 8 + i;
        int pl = c >> 4, kg = c & 15;
        const char* src = btile + pl * 16384 + kg * 1024 + lane * 16;
        __builtin_amdgcn_global_load_lds(
            (const __attribute__((address_space(1))) void*)src,
            (__attribute__((address_space(3))) void*)&lds[32768 + pl * 16384 + kg * 1024], 16, 0, 0);
    }

    // per-wave A staging: wave w owns rows w*64..w*64+63 of each slice
    auto STAGE_A = [&](int buf, int mtn, int ksn) {
        const char* atile = atile0 + (size_t)mtn * 131072;
#pragma unroll
        for (int pl = 0; pl < 2; ++pl)
#pragma unroll
            for (int kgl = 0; kgl < 2; ++kgl) {
                const char* src = atile + pl * 65536 + (2 * ksn + kgl) * 4096 + (w * 64 + lane) * 16;
                char* dst = &lds[buf * 16384 + w * 4096 + pl * 2048 + kgl * 1024];
                __builtin_amdgcn_global_load_lds(
                    (const __attribute__((address_space(1))) void*)src,
                    (__attribute__((address_space(3))) void*)dst, 16, 0, 0);
            }
    };

    i32x16 accH[2][2], accX[2][2];
#pragma unroll
    for (int ap = 0; ap < 2; ++ap)
#pragma unroll
        for (int bp = 0; bp < 2; ++bp) { accH[ap][bp] = (i32x16)(0); accX[ap][bp] = (i32x16)(0); }

    float rm[2], rz[2], rsu[2], rsv[2];
#pragma unroll
    for (int bp = 0; bp < 2; ++bp) { rm[bp] = -INFINITY; rz[bp] = 0.f; rsu[bp] = 0.f; rsv[bp] = 0.f; }

    STAGE_A(0, 0, 0);
    __syncthreads();                           // one-time: B + A(0) visible

    // score*log2(e) = (65536*H + 256*X) * 100*log2(e) / 2^30
    const float S2 = 100.0f * 1.4426950408889634f / 1073741824.0f;
    const float cH = 65536.0f * S2;
    const float cX = 256.0f * S2;

    for (int mt = 0; mt < 4; ++mt) {
#pragma unroll
        for (int ks = 0; ks < 8; ++ks) {
            // 1) issue next slice's staging loads first
            if (mt * 8 + ks < 31)
                STAGE_A((ks + 1) & 1, (ks == 7) ? mt + 1 : mt, (ks == 7) ? 0 : ks + 1);
            const int buf = ks & 1;

            // 2) B-fragment ds_reads (independent of staged A) — fly under the vm wait
            i32x4 bF[2][2];
#pragma unroll
            for (int pl = 0; pl < 2; ++pl)
#pragma unroll
                for (int bp = 0; bp < 2; ++bp) {
                    int kg = ks * 2 + lhi;
                    int cl = bp * 32 + lrow;
                    bF[pl][bp] = *(const i32x4*)&lds[32768 + pl * 16384 + kg * 1024 + cl * 16];
                }

            // 3) drain this slice's A loads (issued last iteration)
            if (mt * 8 + ks < 31)
                asm volatile("s_waitcnt vmcnt(4)" ::: "memory");
            else
                asm volatile("s_waitcnt vmcnt(0)" ::: "memory");

            // 4) A-fragment reads + MFMA
            i32x4 aF[2][2];
#pragma unroll
            for (int pl = 0; pl < 2; ++pl)
#pragma unroll
                for (int ap = 0; ap < 2; ++ap) {
                    int rr = ap * 32 + lrow;
                    aF[pl][ap] = *(const i32x4*)&lds[buf * 16384 + w * 4096 + pl * 2048 + lhi * 1024 + rr * 16];
                }
            __builtin_amdgcn_s_setprio(1);
#pragma unroll
            for (int ap = 0; ap < 2; ++ap)
#pragma unroll
                for (int bp = 0; bp < 2; ++bp) {
                    accH[ap][bp] = __builtin_amdgcn_mfma_i32_32x32x32_i8(aF[0][ap], bF[0][bp], accH[ap][bp], 0, 0, 0);
                    accX[ap][bp] = __builtin_amdgcn_mfma_i32_32x32x32_i8(aF[0][ap], bF[1][bp], accX[ap][bp], 0, 0, 0);
                    accX[ap][bp] = __builtin_amdgcn_mfma_i32_32x32x32_i8(aF[1][ap], bF[0][bp], accX[ap][bp], 0, 0, 0);
                }
            __builtin_amdgcn_s_setprio(0);
        }

        // ---- epilogue for m-tile mt ----
        const int mbase = pixchunk * 1024 + mt * 256 + w * 64;
        const float vcoord = (float)(mbase >> 8);   // constant across the tile
#pragma unroll
        for (int bp = 0; bp < 2; ++bp) {
            // pass 1: integer max over H
            int hm = accH[0][bp][0];
#pragma unroll
            for (int ap = 0; ap < 2; ++ap)
#pragma unroll
                for (int r = 0; r < 16; ++r) {
                    int h = accH[ap][bp][r];
                    hm = (h > hm) ? h : hm;
                }
            const float bx = (float)hm * cH;   // tile base exponent (log2 units)
            // pass 2: exp + moments
            float tz0 = 0.f, tz1 = 0.f, tsur = 0.f;
#pragma unroll
            for (int ap = 0; ap < 2; ++ap)
#pragma unroll
                for (int r = 0; r < 16; ++r) {
                    int dH = accH[ap][bp][r] - hm;                     // exact
                    float e = fexp2(fmaf((float)dH, cH, (float)accX[ap][bp][r] * cX));
                    if (ap == 0) tz0 += e; else tz1 += e;
                    tsur = fmaf(e, (float)((r & 3) + 8 * (r >> 2)), tsur);
                }
            const float ub0 = (float)((mbase & 255) + 4 * lhi);
            const float ub1 = ub0 + 32.0f;
            float tzz = tz0 + tz1;
            float tsu = fmaf(ub0, tz0, fmaf(ub1, tz1, tsur));
            float tsv = vcoord * tzz;
            float nm = fmaxf(rm[bp], bx);
            float f1 = fexp2(rm[bp] - nm), f2 = fexp2(bx - nm);
            rz[bp]  = rz[bp]  * f1 + tzz * f2;
            rsu[bp] = rsu[bp] * f1 + tsu * f2;
            rsv[bp] = rsv[bp] * f1 + tsv * f2;
            rm[bp]  = nm;
#pragma unroll
            for (int ap = 0; ap < 2; ++ap) { accH[ap][bp] = (i32x16)(0); accX[ap][bp] = (i32x16)(0); }
        }
    }

    // ---- merge lane <-> lane+32, write partials ----
#pragma unroll
    for (int bp = 0; bp < 2; ++bp) {
        float m2  = __shfl_xor(rm[bp], 32, 64);
        float z2  = __shfl_xor(rz[bp], 32, 64);
        float su2 = __shfl_xor(rsu[bp], 32, 64);
        float sv2 = __shfl_xor(rsv[bp], 32, 64);
        float nm = fmaxf(rm[bp], m2);
        float f1 = fexp2(rm[bp] - nm), f2 = fexp2(m2 - nm);
        rz[bp]  = rz[bp]  * f1 + z2  * f2;
        rsu[bp] = rsu[bp] * f1 + su2 * f2;
        rsv[bp] = rsv[bp] * f1 + sv2 * f2;
        rm[bp]  = nm;
    }
    if (lane < 32) {
#pragma unroll
        for (int bp = 0; bp < 2; ++bp) {
            int n = kpt * 64 + bp * 32 + lane;
            size_t idx = (((size_t)b * NN + n) * 64 + pixchunk) * 4 + w;
            ((float4*)partials)[idx] = make_float4(rm[bp], rz[bp], rsu[bp], rsv[bp]);
        }
    }
}

// ---------------- combine: one wave per (b,n) row ----------------
__global__ __launch_bounds__(256)
void combine_kernel(const float* __restrict__ partials,
                    const float* __restrict__ kscores,
                    const float* __restrict__ times,
                    float* __restrict__ out) {
    const int wg   = blockIdx.x * 4 + (threadIdx.x >> 6);  // 0..2047 = (b, n)
    const int lane = threadIdx.x & 63;
    const int b = wg >> 10, n = wg & 1023;
    const float4* pp = (const float4*)partials + (size_t)wg * 256;

    float m = -INFINITY, z = 0.f, su = 0.f, sv = 0.f;
#pragma unroll
    for (int i = 0; i < 4; ++i) {
        float4 p = pp[i * 64 + lane];
        float nm = fmaxf(m, p.x);
        float f1 = fexp2(m - nm), f2 = fexp2(p.x - nm);
        z = z * f1 + p.y * f2; su = su * f1 + p.z * f2; sv = sv * f1 + p.w * f2; m = nm;
    }
#pragma unroll
    for (int mask = 32; mask >= 1; mask >>= 1) {
        float m2  = __shfl_xor(m, mask, 64);
        float z2  = __shfl_xor(z, mask, 64);
        float su2 = __shfl_xor(su, mask, 64);
        float sv2 = __shfl_xor(sv, mask, 64);
        float nm = fmaxf(m, m2);
        float f1 = fexp2(m - nm), f2 = fexp2(m2 - nm);
        z = z * f1 + z2 * f2; su = su * f1 + su2 * f2; sv = sv * f1 + sv2 * f2; m = nm;
    }

    if (lane == 0) {
        float u = su / z, v = sv / z;
        out[(size_t)wg * 2 + 0] = u;
        out[(size_t)wg * 2 + 1] = v;
        out[4096 + wg] = kscores[(size_t)(2 * b + 1) * NN + n];
        if (wg == 0) { out[6144] = 1.0f; out[6145] = 3.0f; }

        const float* timg = times + (size_t)(2 * b) * MM;
        float u0 = fminf(fmaxf(floorf(u), 0.f), 255.f);
        float v0 = fminf(fmaxf(floorf(v), 0.f), 255.f);
        float u1 = fminf(u0 + 1.f, 255.f);
        float v1 = fminf(v0 + 1.f, 255.f);
        float au = u - u0, av = v - v0;
        int u0i = (int)u0, u1i = (int)u1, v0i = (int)v0, v1i = (int)v1;
        float t00 = timg[v0i * 256 + u0i], t01 = timg[v0i * 256 + u1i];
        float t10 = timg[v1i * 256 + u0i], t11 = timg[v1i * 256 + u1i];
        float t = t00 * (1.f - au) * (1.f - av) + t01 * au * (1.f - av)
                + t10 * (1.f - au) * av + t11 * au * av;
        out[6146 + wg] = t;
    }
}

extern "C" void kernel_launch(void* const* d_in, const int* in_sizes, int n_in,
                              void* d_out, int out_size, void* d_ws, size_t ws_size,
                              hipStream_t stream) {
    const float* kscores = (const float*)d_in[0];
    const float* kdesc   = (const float*)d_in[1];
    const float* dense   = (const float*)d_in[2];
    const float* times   = (const float*)d_in[3];
    float* out = (float*)d_out;

    char* Ag = (char*)d_ws;                                   // 67,108,864 B
    char* Bg = Ag + (size_t)2 * 256 * 131072;                 //  1,048,576 B
    float* partials = (float*)(Bg + (size_t)2 * 16 * 32768);  //  8,388,608 B

    hipFuncSetAttribute((const void*)gemm_kernel,
                        hipFuncAttributeMaxDynamicSharedMemorySize, 65536);

    hipLaunchKernelGGL(convB_kernel,   dim3(1024), dim3(512), 0, stream, dense, Ag);
    hipLaunchKernelGGL(convA_kernel,   dim3(32),   dim3(256), 0, stream, kdesc, Bg);
    hipLaunchKernelGGL(gemm_kernel,    dim3(2048), dim3(256), 65536, stream, Ag, Bg, partials);
    hipLaunchKernelGGL(combine_kernel, dim3(512),  dim3(256), 0, stream, partials, kscores, times, out);
}

// Round 8
// 167.286 us; speedup vs baseline: 6.3164x; 1.0035x over previous
//
#include <hip/hip_runtime.h>
#include <math.h>

typedef int i32x4 __attribute__((ext_vector_type(4)));
typedef int i32x16 __attribute__((ext_vector_type(16)));

#define CC 248
#define MM 65536
#define NN 1024

__device__ __forceinline__ float fexp2(float x) { return __builtin_amdgcn_exp2f(x); }

// ws: A_tiled [2][256 tiles][pl 2][kg 16][row 256][16]   = 67,108,864 B
//     B_tiled [2][32 ntiles][pl 2][kg 16][col 32][16]    =  1,048,576 B
//     partials [2][1024][32 mchunk][4 wave] float4        =  4,194,304 B

// ---------------- convB: pixel descriptors -> i8 hi/lo planes, tiled ----------------
__global__ __launch_bounds__(512)
void convB_kernel(const float* __restrict__ dense, char* __restrict__ Ag) {
    __shared__ char at[2][16][128][16];       // 64 KB
    __shared__ float scr[4][128];
    const int bid = blockIdx.x;               // 0..1023
    const int fb  = bid >> 9;                 // 0..1 -> frame 2*fb
    const int p0  = (bid & 511) * 128;
    const int tid = threadIdx.x;
    const int row = tid & 127;
    const int q   = tid >> 7;                 // 0..3 -> channels q*64..q*64+63

    const float* dptr = dense + (size_t)(2 * fb) * CC * MM + p0 + row;
    float v[64];
    float ss = 0.f;
#pragma unroll
    for (int i = 0; i < 64; ++i) {
        int c = q * 64 + i;
        float x = (c < CC) ? dptr[(size_t)c * MM] : 0.f;
        v[i] = x;
        ss += x * x;
    }
    scr[q][row] = ss;
    __syncthreads();
    float inv = 32768.0f / fmaxf(sqrtf(scr[0][row] + scr[1][row] + scr[2][row] + scr[3][row]), 1e-12f);

#pragma unroll
    for (int j = 0; j < 16; ++j) {
        unsigned w1 = 0, w0 = 0;
#pragma unroll
        for (int t = 0; t < 4; ++t) {
            float qv = fminf(fmaxf(rintf(v[j * 4 + t] * inv), -32768.f), 32639.f);
            int af = (int)qv;
            int a1 = (af + 128) >> 8;
            int a0 = af - (a1 << 8);
            w1 |= (unsigned)(a1 & 255) << (8 * t);
            w0 |= (unsigned)(a0 & 255) << (8 * t);
        }
        int c0 = q * 64 + j * 4;
        int kg = c0 >> 4, dw = (c0 >> 2) & 3;
        *(unsigned*)&at[0][kg][row][dw * 4] = w1;
        *(unsigned*)&at[1][kg][row][dw * 4] = w0;
    }
    __syncthreads();

    const int tile = p0 >> 8, rhalf = (p0 >> 7) & 1;
    char* outb = Ag + (size_t)(fb * 256 + tile) * 131072;
#pragma unroll
    for (int it = 0; it < 8; ++it) {
        int id = tid + it * 512;              // 0..4095 16B chunks
        int pl = id >> 11, kg = (id >> 7) & 15, r2 = id & 127;
        i32x4 vv = *(const i32x4*)&at[pl][kg][r2][0];
        *(i32x4*)&outb[(size_t)pl * 65536 + kg * 4096 + (rhalf * 128 + r2) * 16] = vv;
    }
}

// ---------------- convA: keypoint descriptors -> i8 hi/lo planes, 32-col tiles ----------------
__global__ __launch_bounds__(256)
void convA_kernel(const float* __restrict__ kdesc, char* __restrict__ Bg) {
    __shared__ char bt[2][16][32][16];        // 16 KB
    __shared__ float scr[8][32];
    const int bid = blockIdx.x;               // 0..63
    const int b   = bid >> 5;
    const int nt  = bid & 31;
    const int n0  = nt * 32;
    const int tid = threadIdx.x;
    const int col = tid & 31;
    const int q   = tid >> 5;                 // 0..7 -> channels q*31..q*31+30

    const float* kp = kdesc + (size_t)(2 * b + 1) * CC * NN + n0 + col;
    float ss = 0.f;
    for (int i = 0; i < 31; ++i) {
        int c = q * 31 + i;
        float v = kp[(size_t)c * NN];
        ss += v * v;
    }
    scr[q][col] = ss;
    __syncthreads();
    float tot = 0.f;
#pragma unroll
    for (int k = 0; k < 8; ++k) tot += scr[k][col];
    float inv = 32768.0f / fmaxf(sqrtf(tot), 1e-12f);
    if (tid < 64) {                            // zero k-pad c=248..255
        int pl = tid >> 5, c2 = tid & 31;
        *(long*)&bt[pl][15][c2][8] = 0L;
    }
    __syncthreads();
    for (int i = 0; i < 31; ++i) {
        int c = q * 31 + i;
        float qq = fminf(fmaxf(rintf(kp[(size_t)c * NN] * inv), -32768.f), 32639.f);
        int af = (int)qq;
        int a1 = (af + 128) >> 8;
        int a0 = af - (a1 << 8);
        bt[0][c >> 4][col][c & 15] = (char)a1;
        bt[1][c >> 4][col][c & 15] = (char)a0;
    }
    __syncthreads();
    char* outb = Bg + (size_t)(b * 32 + nt) * 16384;
    const char* src = &bt[0][0][0][0];
#pragma unroll
    for (int it = 0; it < 4; ++it) {
        int id = tid + it * 256;              // 0..1023 16B chunks
        *(i32x4*)&outb[(size_t)id * 16] = *(const i32x4*)&src[(size_t)id * 16];
    }
}

// ---------------- fused i8 MFMA GEMM: A global->reg ring, B reg-cached, LDS ~free ----------------
// Block: 2048 m (8 mt x 256) x 32 n.  Wave: 64 m-rows x 32 cols, acc 64 regs.
__global__ __launch_bounds__(256, 2)
void gemm_kernel(const char* __restrict__ Ag, const char* __restrict__ Bg,
                 float* __restrict__ partials) {
    __shared__ char lds[16384];               // B tile only

    const int bid  = blockIdx.x;              // 0..2047
    const int xcd  = bid & 7;
    const int slot = bid >> 3;                // 0..255
    const int nt   = slot & 31;
    const int g    = xcd + 8 * (slot >> 5);   // 0..63 -> same (b,mchunk) stays on one XCD
    const int b    = g >> 5;
    const int mchunk = g & 31;

    const int tid  = threadIdx.x;
    const int lane = tid & 63;
    const int w    = tid >> 6;                // 0..3 (wave m-group)
    const int lrow = lane & 31;
    const int lhi  = lane >> 5;

    const char* atile0 = Ag + ((size_t)b * 256 + mchunk * 8) * 131072;
    const char* btile  = Bg + (size_t)(b * 32 + nt) * 16384;

    // ---- stage B (16 KB, cooperative) ----
#pragma unroll
    for (int i = 0; i < 4; ++i) {
        int c = w * 4 + i;                     // 0..15 1KB chunks
        __builtin_amdgcn_global_load_lds(
            (const __attribute__((address_space(1))) void*)(btile + c * 1024 + lane * 16),
            (__attribute__((address_space(3))) void*)&lds[c * 1024], 16, 0, 0);
    }
    __syncthreads();                           // B visible (compiler drains vmem before barrier)

    // per-lane invariant offsets
    const int arow_off = (w * 64 + lrow) * 16 + lhi * 4096;   // + ap*512 + pl*65536 + mt*131072 + ks*8192
    const int boff     = lhi * 512 + lrow * 16;               // + pl*8192 + ks*1024

    i32x16 accH[2], accX[2];
#pragma unroll
    for (int ap = 0; ap < 2; ++ap) { accH[ap] = (i32x16)(0); accX[ap] = (i32x16)(0); }

    i32x4 abuf[4][2][2];   // [ring][pl][ap]
    i32x4 bc[8][2];        // [ks][pl] — mt-invariant, cached in regs after mt 0

    auto LOADA = [&](int ring, int s) {
        const int mtn = s >> 3, ksn = s & 7;
        const char* base = atile0 + mtn * 131072 + ksn * 8192 + arow_off;
#pragma unroll
        for (int pl = 0; pl < 2; ++pl)
#pragma unroll
            for (int ap = 0; ap < 2; ++ap)
                abuf[ring][pl][ap] = *(const i32x4*)(base + pl * 65536 + ap * 512);
    };

    float rm = -INFINITY, rz = 0.f, rsu = 0.f, rsv = 0.f;

    const float S2 = 100.0f * 1.4426950408889634f / 1073741824.0f;  // 100*log2e/2^30
    const float cH = 65536.0f * S2;
    const float cX = 256.0f * S2;

    LOADA(0, 0);
    LOADA(1, 1);

    // epilogue for one finished mt (per lane: one column, 32 row-values)
    auto EPI = [&](int mt) {
        const int mbase = mchunk * 2048 + mt * 256 + w * 64;     // 64-aligned
        int hm = accH[0][0];
#pragma unroll
        for (int ap = 0; ap < 2; ++ap)
#pragma unroll
            for (int r = 0; r < 16; ++r) {
                int h = accH[ap][r];
                hm = (h > hm) ? h : hm;
            }
        const float bx = (float)hm * cH;
        float tz0 = 0.f, tz1 = 0.f, tsur = 0.f;
#pragma unroll
        for (int ap = 0; ap < 2; ++ap)
#pragma unroll
            for (int r = 0; r < 16; ++r) {
                int dH = accH[ap][r] - hm;                       // exact
                float e = fexp2(fmaf((float)dH, cH, (float)accX[ap][r] * cX));
                if (ap == 0) tz0 += e; else tz1 += e;
                tsur = fmaf(e, (float)((r & 3) + 8 * (r >> 2)), tsur);
            }
        const float ub0 = (float)((mbase & 255) + 4 * lhi);
        const float ub1 = ub0 + 32.0f;
        const float vcoord = (float)(mbase >> 8);                // constant for the wave-tile
        float tzz = tz0 + tz1;
        float tsu = fmaf(ub0, tz0, fmaf(ub1, tz1, tsur));
        float tsv = vcoord * tzz;
        float nm = fmaxf(rm, bx);
        float f1 = fexp2(rm - nm), f2 = fexp2(bx - nm);
        rz  = rz  * f1 + tzz * f2;
        rsu = rsu * f1 + tsu * f2;
        rsv = rsv * f1 + tsv * f2;
        rm  = nm;
#pragma unroll
        for (int ap = 0; ap < 2; ++ap) { accH[ap] = (i32x16)(0); accX[ap] = (i32x16)(0); }
    };

    // ---- mt = 0: read bF from LDS (cache into bc) + compute ----
#pragma unroll
    for (int ks = 0; ks < 8; ++ks) {
        bc[ks][0] = *(const i32x4*)&lds[ks * 1024 + boff];
        bc[ks][1] = *(const i32x4*)&lds[8192 + ks * 1024 + boff];
        LOADA((ks + 2) & 3, ks + 2);
        __builtin_amdgcn_s_setprio(1);
#pragma unroll
        for (int ap = 0; ap < 2; ++ap) {
            accH[ap] = __builtin_amdgcn_mfma_i32_32x32x32_i8(abuf[ks & 3][0][ap], bc[ks][0], accH[ap], 0, 0, 0);
            accX[ap] = __builtin_amdgcn_mfma_i32_32x32x32_i8(abuf[ks & 3][0][ap], bc[ks][1], accX[ap], 0, 0, 0);
            accX[ap] = __builtin_amdgcn_mfma_i32_32x32x32_i8(abuf[ks & 3][1][ap], bc[ks][0], accX[ap], 0, 0, 0);
        }
        __builtin_amdgcn_s_setprio(0);
    }
    EPI(0);

    // ---- mt = 1..7: pure register B, global-ring A ----
#pragma unroll
    for (int mt = 1; mt < 8; ++mt) {
#pragma unroll
        for (int ks = 0; ks < 8; ++ks) {
            const int s = mt * 8 + ks;
            if (s + 2 < 64) LOADA((s + 2) & 3, s + 2);
            __builtin_amdgcn_s_setprio(1);
#pragma unroll
            for (int ap = 0; ap < 2; ++ap) {
                accH[ap] = __builtin_amdgcn_mfma_i32_32x32x32_i8(abuf[s & 3][0][ap], bc[ks][0], accH[ap], 0, 0, 0);
                accX[ap] = __builtin_amdgcn_mfma_i32_32x32x32_i8(abuf[s & 3][0][ap], bc[ks][1], accX[ap], 0, 0, 0);
                accX[ap] = __builtin_amdgcn_mfma_i32_32x32x32_i8(abuf[s & 3][1][ap], bc[ks][0], accX[ap], 0, 0, 0);
            }
            __builtin_amdgcn_s_setprio(0);
        }
        EPI(mt);
    }

    // ---- merge lane <-> lane+32 (same column, other row half), write partials ----
    {
        float m2  = __shfl_xor(rm, 32, 64);
        float z2  = __shfl_xor(rz, 32, 64);
        float su2 = __shfl_xor(rsu, 32, 64);
        float sv2 = __shfl_xor(rsv, 32, 64);
        float nm = fmaxf(rm, m2);
        float f1 = fexp2(rm - nm), f2 = fexp2(m2 - nm);
        rz  = rz  * f1 + z2  * f2;
        rsu = rsu * f1 + su2 * f2;
        rsv = rsv * f1 + sv2 * f2;
        rm  = nm;
    }
    if (lane < 32) {
        int n = nt * 32 + lrow;
        size_t idx = (((size_t)b * NN + n) * 32 + mchunk) * 4 + w;
        ((float4*)partials)[idx] = make_float4(rm, rz, rsu, rsv);
    }
}

// ---------------- combine: one wave per (b,n) row, 128 partials each ----------------
__global__ __launch_bounds__(256)
void combine_kernel(const float* __restrict__ partials,
                    const float* __restrict__ kscores,
                    const float* __restrict__ times,
                    float* __restrict__ out) {
    const int wg   = blockIdx.x * 4 + (threadIdx.x >> 6);  // 0..2047 = (b, n)
    const int lane = threadIdx.x & 63;
    const int b = wg >> 10, n = wg & 1023;
    const float4* pp = (const float4*)partials + (size_t)wg * 128;

    float m = -INFINITY, z = 0.f, su = 0.f, sv = 0.f;
#pragma unroll
    for (int i = 0; i < 2; ++i) {
        float4 p = pp[i * 64 + lane];
        float nm = fmaxf(m, p.x);
        float f1 = fexp2(m - nm), f2 = fexp2(p.x - nm);
        z = z * f1 + p.y * f2; su = su * f1 + p.z * f2; sv = sv * f1 + p.w * f2; m = nm;
    }
#pragma unroll
    for (int mask = 32; mask >= 1; mask >>= 1) {
        float m2  = __shfl_xor(m, mask, 64);
        float z2  = __shfl_xor(z, mask, 64);
        float su2 = __shfl_xor(su, mask, 64);
        float sv2 = __shfl_xor(sv, mask, 64);
        float nm = fmaxf(m, m2);
        float f1 = fexp2(m - nm), f2 = fexp2(m2 - nm);
        z = z * f1 + z2 * f2; su = su * f1 + su2 * f2; sv = sv * f1 + sv2 * f2; m = nm;
    }

    if (lane == 0) {
        float u = su / z, v = sv / z;
        out[(size_t)wg * 2 + 0] = u;
        out[(size_t)wg * 2 + 1] = v;
        out[4096 + wg] = kscores[(size_t)(2 * b + 1) * NN + n];
        if (wg == 0) { out[6144] = 1.0f; out[6145] = 3.0f; }

        const float* timg = times + (size_t)(2 * b) * MM;
        float u0 = fminf(fmaxf(floorf(u), 0.f), 255.f);
        float v0 = fminf(fmaxf(floorf(v), 0.f), 255.f);
        float u1 = fminf(u0 + 1.f, 255.f);
        float v1 = fminf(v0 + 1.f, 255.f);
        float au = u - u0, av = v - v0;
        int u0i = (int)u0, u1i = (int)u1, v0i = (int)v0, v1i = (int)v1;
        float t00 = timg[v0i * 256 + u0i], t01 = timg[v0i * 256 + u1i];
        float t10 = timg[v1i * 256 + u0i], t11 = timg[v1i * 256 + u1i];
        float t = t00 * (1.f - au) * (1.f - av) + t01 * au * (1.f - av)
                + t10 * (1.f - au) * av + t11 * au * av;
        out[6146 + wg] = t;
    }
}

extern "C" void kernel_launch(void* const* d_in, const int* in_sizes, int n_in,
                              void* d_out, int out_size, void* d_ws, size_t ws_size,
                              hipStream_t stream) {
    const float* kscores = (const float*)d_in[0];
    const float* kdesc   = (const float*)d_in[1];
    const float* dense   = (const float*)d_in[2];
    const float* times   = (const float*)d_in[3];
    float* out = (float*)d_out;

    char* Ag = (char*)d_ws;                                   // 67,108,864 B
    char* Bg = Ag + (size_t)2 * 256 * 131072;                 //  1,048,576 B
    float* partials = (float*)(Bg + (size_t)2 * 32 * 16384);  //  4,194,304 B

    hipLaunchKernelGGL(convB_kernel,   dim3(1024), dim3(512), 0, stream, dense, Ag);
    hipLaunchKernelGGL(convA_kernel,   dim3(64),   dim3(256), 0, stream, kdesc, Bg);
    hipLaunchKernelGGL(gemm_kernel,    dim3(2048), dim3(256), 0, stream, Ag, Bg, partials);
    hipLaunchKernelGGL(combine_kernel, dim3(512),  dim3(256), 0, stream, partials, kscores, times, out);
}

// Round 10
// 154.678 us; speedup vs baseline: 6.8313x; 1.0815x over previous
//
#include <hip/hip_runtime.h>
#include <math.h>

typedef int i32x4 __attribute__((ext_vector_type(4)));
typedef int i32x16 __attribute__((ext_vector_type(16)));

#define CC 248
#define MM 65536
#define NN 1024

__device__ __forceinline__ float fexp2(float x) { return __builtin_amdgcn_exp2f(x); }

// ws: A_tiled [2][256 tiles][pl 2][kg 16][row 256][16]   = 67,108,864 B
//     B_tiled [2][32 ntiles][pl 2][kg 16][col 32][16]    =  1,048,576 B
//     partials [2][1024][32 mchunk] float4                =  1,048,576 B

// ---------------- convB: pixel descriptors -> i8 hi/lo planes, tiled ----------------
__global__ __launch_bounds__(512)
void convB_kernel(const float* __restrict__ dense, char* __restrict__ Ag) {
    __shared__ char at[2][16][128][16];       // 64 KB
    __shared__ float scr[4][128];
    const int bid = blockIdx.x;               // 0..1023
    const int fb  = bid >> 9;                 // 0..1 -> frame 2*fb
    const int p0  = (bid & 511) * 128;
    const int tid = threadIdx.x;
    const int row = tid & 127;
    const int q   = tid >> 7;                 // 0..3 -> channels q*64..q*64+63

    const float* dptr = dense + (size_t)(2 * fb) * CC * MM + p0 + row;
    float v[64];
    float ss = 0.f;
#pragma unroll
    for (int i = 0; i < 64; ++i) {
        int c = q * 64 + i;
        float x = (c < CC) ? dptr[(size_t)c * MM] : 0.f;
        v[i] = x;
        ss += x * x;
    }
    scr[q][row] = ss;
    __syncthreads();
    float inv = 32768.0f / fmaxf(sqrtf(scr[0][row] + scr[1][row] + scr[2][row] + scr[3][row]), 1e-12f);

#pragma unroll
    for (int j = 0; j < 16; ++j) {
        unsigned w1 = 0, w0 = 0;
#pragma unroll
        for (int t = 0; t < 4; ++t) {
            float qv = fminf(fmaxf(rintf(v[j * 4 + t] * inv), -32768.f), 32639.f);
            int af = (int)qv;
            int a1 = (af + 128) >> 8;
            int a0 = af - (a1 << 8);
            w1 |= (unsigned)(a1 & 255) << (8 * t);
            w0 |= (unsigned)(a0 & 255) << (8 * t);
        }
        int c0 = q * 64 + j * 4;
        int kg = c0 >> 4, dw = (c0 >> 2) & 3;
        *(unsigned*)&at[0][kg][row][dw * 4] = w1;
        *(unsigned*)&at[1][kg][row][dw * 4] = w0;
    }
    __syncthreads();

    const int tile = p0 >> 8, rhalf = (p0 >> 7) & 1;
    char* outb = Ag + (size_t)(fb * 256 + tile) * 131072;
#pragma unroll
    for (int it = 0; it < 8; ++it) {
        int id = tid + it * 512;              // 0..4095 16B chunks
        int pl = id >> 11, kg = (id >> 7) & 15, r2 = id & 127;
        i32x4 vv = *(const i32x4*)&at[pl][kg][r2][0];
        *(i32x4*)&outb[(size_t)pl * 65536 + kg * 4096 + (rhalf * 128 + r2) * 16] = vv;
    }
}

// ---------------- convA: keypoint descriptors -> i8 hi/lo planes, 32-col tiles ----------------
__global__ __launch_bounds__(256)
void convA_kernel(const float* __restrict__ kdesc, char* __restrict__ Bg) {
    __shared__ char bt[2][16][32][16];        // 16 KB
    __shared__ float scr[8][32];
    const int bid = blockIdx.x;               // 0..63
    const int b   = bid >> 5;
    const int nt  = bid & 31;
    const int n0  = nt * 32;
    const int tid = threadIdx.x;
    const int col = tid & 31;
    const int q   = tid >> 5;                 // 0..7 -> channels q*31..q*31+30

    const float* kp = kdesc + (size_t)(2 * b + 1) * CC * NN + n0 + col;
    float ss = 0.f;
    for (int i = 0; i < 31; ++i) {
        int c = q * 31 + i;
        float v = kp[(size_t)c * NN];
        ss += v * v;
    }
    scr[q][col] = ss;
    __syncthreads();
    float tot = 0.f;
#pragma unroll
    for (int k = 0; k < 8; ++k) tot += scr[k][col];
    float inv = 32768.0f / fmaxf(sqrtf(tot), 1e-12f);
    if (tid < 64) {                            // zero k-pad c=248..255
        int pl = tid >> 5, c2 = tid & 31;
        *(long*)&bt[pl][15][c2][8] = 0L;
    }
    __syncthreads();
    for (int i = 0; i < 31; ++i) {
        int c = q * 31 + i;
        float qq = fminf(fmaxf(rintf(kp[(size_t)c * NN] * inv), -32768.f), 32639.f);
        int af = (int)qq;
        int a1 = (af + 128) >> 8;
        int a0 = af - (a1 << 8);
        bt[0][c >> 4][col][c & 15] = (char)a1;
        bt[1][c >> 4][col][c & 15] = (char)a0;
    }
    __syncthreads();
    char* outb = Bg + (size_t)(b * 32 + nt) * 16384;
    const char* src = &bt[0][0][0][0];
#pragma unroll
    for (int it = 0; it < 4; ++it) {
        int id = tid + it * 256;              // 0..1023 16B chunks
        *(i32x4*)&outb[(size_t)id * 16] = *(const i32x4*)&src[(size_t)id * 16];
    }
}

// ---------------- fused i8 MFMA GEMM: A shared in LDS (counted-vmcnt ring), B in regs ----------------
// Block: 8 waves, slice tile 64m x 256n, 32 mt-passes (BM=2048), full K per slice step.
// LDS ring: 4 slots x 4 KB; slot = s&3; layout slot*4096 + pl*2048 + kgl*1024 + row*16.
__global__ __launch_bounds__(512, 2)
void gemm_kernel(const char* __restrict__ Ag, const char* __restrict__ Bg,
                 float* __restrict__ partials) {
    __shared__ char lds[16384];

    const int bid = blockIdx.x;               // 0..255 (= 1 block/CU)
    const int xcd = bid & 7;
    const int idx = bid >> 3;                 // 0..31
    const int bm  = xcd + 8 * (idx >> 2);     // 0..63 : blocks sharing A-panel -> same XCD
    const int nchunk = idx & 3;               // 0..3
    const int b      = bm >> 5;
    const int mchunk = bm & 31;

    const int tid  = threadIdx.x;
    const int lane = tid & 63;
    const int w    = tid >> 6;                // 0..7
    const int lrow = lane & 31;
    const int lhi  = lane >> 5;

    const char* atile0 = Ag + ((size_t)b * 256 + mchunk * 8) * 131072;   // 8 tiles of 256 rows

    // ---- B: load this wave's 32-n column block, full K, into registers (once) ----
    // B_tiled per nt: pl stride 8192, kg stride 512 (32 cols x 16 B), col stride 16.
    i32x4 bc[8][2];
    {
        const char* btile = Bg + (size_t)(b * 32 + nchunk * 8 + w) * 16384;
#pragma unroll
        for (int ks = 0; ks < 8; ++ks)
#pragma unroll
            for (int pl = 0; pl < 2; ++pl)
                bc[ks][pl] = *(const i32x4*)(btile + pl * 8192 + (ks * 2 + lhi) * 512 + lrow * 16);
    }

    // staging: waves 0..3 each own one (pl,kgl) 1KB chunk per slice
    auto ISSUE = [&](int s) {
        const int mtn = s >> 3, ksn = s & 7;
        const int tile = mtn >> 2, rowb = (mtn & 3) * 64;
        const char* src = atile0 + (size_t)tile * 131072 + (w >> 1) * 65536
                        + (ksn * 2 + (w & 1)) * 4096 + (rowb + lane) * 16;
        char* dst = &lds[(s & 3) * 4096 + (w >> 1) * 2048 + (w & 1) * 1024];
        __builtin_amdgcn_global_load_lds(
            (const __attribute__((address_space(1))) void*)src,
            (__attribute__((address_space(3))) void*)dst, 16, 0, 0);
    };

    i32x16 accH[2], accX[2];
#pragma unroll
    for (int ap = 0; ap < 2; ++ap) { accH[ap] = (i32x16)(0); accX[ap] = (i32x16)(0); }
    float rm = -INFINITY, rz = 0.f, rsu = 0.f, rsv = 0.f;

    const float S2 = 100.0f * 1.4426950408889634f / 1073741824.0f;  // 100*log2e/2^30
    const float cH = 65536.0f * S2;
    const float cX = 256.0f * S2;

    const bool stager = (w < 4);
    if (stager) { ISSUE(0); ISSUE(1); ISSUE(2); }   // 3 slices in flight

    // one slice: wait own chunk (counted), barrier, prefetch s+3, ds_read + 6 MFMA
    auto SLICE = [&](int mt, int ks, int waitn, bool issue) {
        const int s = mt * 8 + ks;
        if (stager) {
            if (waitn == 2)      asm volatile("s_waitcnt vmcnt(2)" ::: "memory");
            else if (waitn == 1) asm volatile("s_waitcnt vmcnt(1)" ::: "memory");
            else                 asm volatile("s_waitcnt vmcnt(0)" ::: "memory");
        }
        asm volatile("s_barrier" ::: "memory");
        if (stager && issue) ISSUE(s + 3);

        i32x4 aF[2][2];
#pragma unroll
        for (int pl = 0; pl < 2; ++pl)
#pragma unroll
            for (int ap = 0; ap < 2; ++ap)
                aF[pl][ap] = *(const i32x4*)&lds[(ks & 3) * 4096 + pl * 2048 + lhi * 1024 + (ap * 32 + lrow) * 16];
        __builtin_amdgcn_s_setprio(1);
#pragma unroll
        for (int ap = 0; ap < 2; ++ap) {
            accH[ap] = __builtin_amdgcn_mfma_i32_32x32x32_i8(aF[0][ap], bc[ks][0], accH[ap], 0, 0, 0);
            accX[ap] = __builtin_amdgcn_mfma_i32_32x32x32_i8(aF[0][ap], bc[ks][1], accX[ap], 0, 0, 0);
            accX[ap] = __builtin_amdgcn_mfma_i32_32x32x32_i8(aF[1][ap], bc[ks][0], accX[ap], 0, 0, 0);
        }
        __builtin_amdgcn_s_setprio(0);
    };

    auto EPI = [&](int mt) {
        const int mbase = mchunk * 2048 + mt * 64;
        int hm = accH[0][0];
#pragma unroll
        for (int ap = 0; ap < 2; ++ap)
#pragma unroll
            for (int r = 0; r < 16; ++r) {
                int h = accH[ap][r];
                hm = (h > hm) ? h : hm;
            }
        const float bx = (float)hm * cH;
        float tz0 = 0.f, tz1 = 0.f, tsur = 0.f;
#pragma unroll
        for (int ap = 0; ap < 2; ++ap)
#pragma unroll
            for (int r = 0; r < 16; ++r) {
                int dH = accH[ap][r] - hm;                       // exact
                float e = fexp2(fmaf((float)dH, cH, (float)accX[ap][r] * cX));
                if (ap == 0) tz0 += e; else tz1 += e;
                tsur = fmaf(e, (float)((r & 3) + 8 * (r >> 2)), tsur);
            }
        const float ub0 = (float)((mbase & 255) + 4 * lhi);
        const float ub1 = ub0 + 32.0f;
        const float vcoord = (float)(mbase >> 8);
        float tzz = tz0 + tz1;
        float tsu = fmaf(ub0, tz0, fmaf(ub1, tz1, tsur));
        float tsv = vcoord * tzz;
        float nm = fmaxf(rm, bx);
        float f1 = fexp2(rm - nm), f2 = fexp2(bx - nm);
        rz  = rz  * f1 + tzz * f2;
        rsu = rsu * f1 + tsu * f2;
        rsv = rsv * f1 + tsv * f2;
        rm  = nm;
#pragma unroll
        for (int ap = 0; ap < 2; ++ap) { accH[ap] = (i32x16)(0); accX[ap] = (i32x16)(0); }
    };

    // ---- mt = 0..30: uniform (wait vmcnt(2), always prefetch) ----
    for (int mt = 0; mt < 31; ++mt) {
#pragma unroll
        for (int ks = 0; ks < 8; ++ks)
            SLICE(mt, ks, 2, true);
        EPI(mt);
    }
    // ---- mt = 31: tail ----
    SLICE(31, 0, 2, true);   // s=248 -> issue 251
    SLICE(31, 1, 2, true);   // 252
    SLICE(31, 2, 2, true);   // 253
    SLICE(31, 3, 2, true);   // 254
    SLICE(31, 4, 2, true);   // 255
    SLICE(31, 5, 2, false);
    SLICE(31, 6, 1, false);
    SLICE(31, 7, 0, false);
    EPI(31);

    // ---- merge lane <-> lane+32 (same column, other row half), write partials ----
    {
        float m2  = __shfl_xor(rm, 32, 64);
        float z2  = __shfl_xor(rz, 32, 64);
        float su2 = __shfl_xor(rsu, 32, 64);
        float sv2 = __shfl_xor(rsv, 32, 64);
        float nm = fmaxf(rm, m2);
        float f1 = fexp2(rm - nm), f2 = fexp2(m2 - nm);
        rz  = rz  * f1 + z2  * f2;
        rsu = rsu * f1 + su2 * f2;
        rsv = rsv * f1 + sv2 * f2;
        rm  = nm;
    }
    if (lane < 32) {
        int n = (nchunk * 8 + w) * 32 + lrow;
        size_t idxp = ((size_t)b * NN + n) * 32 + mchunk;
        ((float4*)partials)[idxp] = make_float4(rm, rz, rsu, rsv);
    }
}

// ---------------- combine: one wave per (b,n) row, 32 partials each ----------------
__global__ __launch_bounds__(256)
void combine_kernel(const float* __restrict__ partials,
                    const float* __restrict__ kscores,
                    const float* __restrict__ times,
                    float* __restrict__ out) {
    const int wg   = blockIdx.x * 4 + (threadIdx.x >> 6);  // 0..2047 = (b, n)
    const int lane = threadIdx.x & 63;
    const int b = wg >> 10, n = wg & 1023;
    const float4* pp = (const float4*)partials + (size_t)wg * 32;

    float m = -INFINITY, z = 0.f, su = 0.f, sv = 0.f;
    if (lane < 32) {
        float4 p = pp[lane];
        m = p.x; z = p.y; su = p.z; sv = p.w;
    }
#pragma unroll
    for (int mask = 16; mask >= 1; mask >>= 1) {
        float m2  = __shfl_xor(m, mask, 64);
        float z2  = __shfl_xor(z, mask, 64);
        float su2 = __shfl_xor(su, mask, 64);
        float sv2 = __shfl_xor(sv, mask, 64);
        float nm = fmaxf(m, m2);
        float f1 = fexp2(m - nm), f2 = fexp2(m2 - nm);
        z = z * f1 + z2 * f2; su = su * f1 + su2 * f2; sv = sv * f1 + sv2 * f2; m = nm;
    }

    if (lane == 0) {
        float u = su / z, v = sv / z;
        out[(size_t)wg * 2 + 0] = u;
        out[(size_t)wg * 2 + 1] = v;
        out[4096 + wg] = kscores[(size_t)(2 * b + 1) * NN + n];
        if (wg == 0) { out[6144] = 1.0f; out[6145] = 3.0f; }

        const float* timg = times + (size_t)(2 * b) * MM;
        float u0 = fminf(fmaxf(floorf(u), 0.f), 255.f);
        float v0 = fminf(fmaxf(floorf(v), 0.f), 255.f);
        float u1 = fminf(u0 + 1.f, 255.f);
        float v1 = fminf(v0 + 1.f, 255.f);
        float au = u - u0, av = v - v0;
        int u0i = (int)u0, u1i = (int)u1, v0i = (int)v0, v1i = (int)v1;
        float t00 = timg[v0i * 256 + u0i], t01 = timg[v0i * 256 + u1i];
        float t10 = timg[v1i * 256 + u0i], t11 = timg[v1i * 256 + u1i];
        float t = t00 * (1.f - au) * (1.f - av) + t01 * au * (1.f - av)
                + t10 * (1.f - au) * av + t11 * au * av;
        out[6146 + wg] = t;
    }
}

extern "C" void kernel_launch(void* const* d_in, const int* in_sizes, int n_in,
                              void* d_out, int out_size, void* d_ws, size_t ws_size,
                              hipStream_t stream) {
    const float* kscores = (const float*)d_in[0];
    const float* kdesc   = (const float*)d_in[1];
    const float* dense   = (const float*)d_in[2];
    const float* times   = (const float*)d_in[3];
    float* out = (float*)d_out;

    char* Ag = (char*)d_ws;                                   // 67,108,864 B
    char* Bg = Ag + (size_t)2 * 256 * 131072;                 //  1,048,576 B
    float* partials = (float*)(Bg + (size_t)2 * 32 * 16384);  //  1,048,576 B

    hipLaunchKernelGGL(convB_kernel,   dim3(1024), dim3(512), 0, stream, dense, Ag);
    hipLaunchKernelGGL(convA_kernel,   dim3(64),   dim3(256), 0, stream, kdesc, Bg);
    hipLaunchKernelGGL(gemm_kernel,    dim3(256),  dim3(512), 0, stream, Ag, Bg, partials);
    hipLaunchKernelGGL(combine_kernel, dim3(512),  dim3(256), 0, stream, partials, kscores, times, out);
}

// Round 11
// 147.513 us; speedup vs baseline: 7.1631x; 1.0486x over previous
//
#include <hip/hip_runtime.h>
#include <math.h>

typedef int i32x4 __attribute__((ext_vector_type(4)));
typedef int i32x16 __attribute__((ext_vector_type(16)));

#define CC 248
#define MM 65536
#define NN 1024

__device__ __forceinline__ float fexp2(float x) { return __builtin_amdgcn_exp2f(x); }

// ws: A_tiled [2][256 tiles][pl 2][kg 16][row 256][16]   = 67,108,864 B
//     B_tiled [2][32 ntiles][pl 2][kg 16][col 32][16]    =  1,048,576 B
//     partials [2][1024][64 mchunk] float4                =  2,097,152 B

// ---------------- convB: pixel descriptors -> i8 hi/lo planes, tiled ----------------
__global__ __launch_bounds__(512)
void convB_kernel(const float* __restrict__ dense, char* __restrict__ Ag) {
    __shared__ char at[2][16][128][16];       // 64 KB
    __shared__ float scr[4][128];
    const int bid = blockIdx.x;               // 0..1023
    const int fb  = bid >> 9;                 // 0..1 -> frame 2*fb
    const int p0  = (bid & 511) * 128;
    const int tid = threadIdx.x;
    const int row = tid & 127;
    const int q   = tid >> 7;                 // 0..3 -> channels q*64..q*64+63

    const float* dptr = dense + (size_t)(2 * fb) * CC * MM + p0 + row;
    float v[64];
    float ss = 0.f;
#pragma unroll
    for (int i = 0; i < 64; ++i) {
        int c = q * 64 + i;
        float x = (c < CC) ? dptr[(size_t)c * MM] : 0.f;
        v[i] = x;
        ss += x * x;
    }
    scr[q][row] = ss;
    __syncthreads();
    float inv = 32768.0f / fmaxf(sqrtf(scr[0][row] + scr[1][row] + scr[2][row] + scr[3][row]), 1e-12f);

#pragma unroll
    for (int j = 0; j < 16; ++j) {
        unsigned w1 = 0, w0 = 0;
#pragma unroll
        for (int t = 0; t < 4; ++t) {
            float qv = fminf(fmaxf(rintf(v[j * 4 + t] * inv), -32768.f), 32639.f);
            int af = (int)qv;
            int a1 = (af + 128) >> 8;
            int a0 = af - (a1 << 8);
            w1 |= (unsigned)(a1 & 255) << (8 * t);
            w0 |= (unsigned)(a0 & 255) << (8 * t);
        }
        int c0 = q * 64 + j * 4;
        int kg = c0 >> 4, dw = (c0 >> 2) & 3;
        *(unsigned*)&at[0][kg][row][dw * 4] = w1;
        *(unsigned*)&at[1][kg][row][dw * 4] = w0;
    }
    __syncthreads();

    const int tile = p0 >> 8, rhalf = (p0 >> 7) & 1;
    char* outb = Ag + (size_t)(fb * 256 + tile) * 131072;
#pragma unroll
    for (int it = 0; it < 8; ++it) {
        int id = tid + it * 512;              // 0..4095 16B chunks
        int pl = id >> 11, kg = (id >> 7) & 15, r2 = id & 127;
        i32x4 vv = *(const i32x4*)&at[pl][kg][r2][0];
        *(i32x4*)&outb[(size_t)pl * 65536 + kg * 4096 + (rhalf * 128 + r2) * 16] = vv;
    }
}

// ---------------- convA: keypoint descriptors -> i8 hi/lo planes, 32-col tiles ----------------
__global__ __launch_bounds__(256)
void convA_kernel(const float* __restrict__ kdesc, char* __restrict__ Bg) {
    __shared__ char bt[2][16][32][16];        // 16 KB
    __shared__ float scr[8][32];
    const int bid = blockIdx.x;               // 0..63
    const int b   = bid >> 5;
    const int nt  = bid & 31;
    const int n0  = nt * 32;
    const int tid = threadIdx.x;
    const int col = tid & 31;
    const int q   = tid >> 5;                 // 0..7 -> channels q*31..q*31+30

    const float* kp = kdesc + (size_t)(2 * b + 1) * CC * NN + n0 + col;
    float ss = 0.f;
    for (int i = 0; i < 31; ++i) {
        int c = q * 31 + i;
        float v = kp[(size_t)c * NN];
        ss += v * v;
    }
    scr[q][col] = ss;
    __syncthreads();
    float tot = 0.f;
#pragma unroll
    for (int k = 0; k < 8; ++k) tot += scr[k][col];
    float inv = 32768.0f / fmaxf(sqrtf(tot), 1e-12f);
    if (tid < 64) {                            // zero k-pad c=248..255
        int pl = tid >> 5, c2 = tid & 31;
        *(long*)&bt[pl][15][c2][8] = 0L;
    }
    __syncthreads();
    for (int i = 0; i < 31; ++i) {
        int c = q * 31 + i;
        float qq = fminf(fmaxf(rintf(kp[(size_t)c * NN] * inv), -32768.f), 32639.f);
        int af = (int)qq;
        int a1 = (af + 128) >> 8;
        int a0 = af - (a1 << 8);
        bt[0][c >> 4][col][c & 15] = (char)a1;
        bt[1][c >> 4][col][c & 15] = (char)a0;
    }
    __syncthreads();
    char* outb = Bg + (size_t)(b * 32 + nt) * 16384;
    const char* src = &bt[0][0][0][0];
#pragma unroll
    for (int it = 0; it < 4; ++it) {
        int id = tid + it * 256;              // 0..1023 16B chunks
        *(i32x4*)&outb[(size_t)id * 16] = *(const i32x4*)&src[(size_t)id * 16];
    }
}

// ---------------- fused i8 MFMA GEMM: n=64/wave, A ring in LDS, B-hi in regs, B-lo in LDS ----
// Block: 4 waves, BN=256 (64 n per wave), BM=1024 (16 mt of 64 rows), 128 slices.
// LDS: A ring 3 x 4096 [pl2][kgl2][row64][16] at 0;  B0 (lo plane) 64 KB at 12288
//      [tile 8][kg 16][col 32][16].
__global__ __launch_bounds__(256, 2)
void gemm_kernel(const char* __restrict__ Ag, const char* __restrict__ Bg,
                 float* __restrict__ partials) {
    extern __shared__ char lds[];
    const int B0OFF = 12288;

    const int bid  = blockIdx.x;              // 0..511
    const int xcd  = bid & 7;
    const int rest = bid >> 3;                // 0..63
    const int nchunk = rest & 3;
    const int pid  = xcd + 8 * (rest >> 2);   // 0..127 : A-panel sharers -> same XCD
    const int b      = pid >> 6;
    const int mchunk = pid & 63;              // BM = 1024

    const int tid  = threadIdx.x;
    const int lane = tid & 63;
    const int w    = tid >> 6;                // 0..3
    const int lrow = lane & 31;
    const int lhi  = lane >> 5;

    const char* atile0 = Ag + ((size_t)b * 256 + mchunk * 4) * 131072;  // 4 tiles of 256 rows
    const char* bbase  = Bg + (size_t)(b * 32 + nchunk * 8) * 16384;    // 8 n-tiles

    // ---- stage B0 (lo plane of 8 tiles, 64 KB) ----
#pragma unroll
    for (int i = 0; i < 16; ++i) {
        int c = w * 16 + i;                    // 0..63 1KB chunks
        int t = c >> 3, j = c & 7;
        const char* src = bbase + t * 16384 + 8192 + j * 1024 + lane * 16;
        __builtin_amdgcn_global_load_lds(
            (const __attribute__((address_space(1))) void*)src,
            (__attribute__((address_space(3))) void*)&lds[B0OFF + t * 8192 + j * 1024], 16, 0, 0);
    }

    // ---- bc: b1 (hi plane), full K, this wave's 2 n-tiles -> 64 regs ----
    i32x4 bc[8][2];
#pragma unroll
    for (int ks = 0; ks < 8; ++ks)
#pragma unroll
        for (int bp = 0; bp < 2; ++bp)
            bc[ks][bp] = *(const i32x4*)(bbase + (size_t)(2 * w + bp) * 16384
                                         + (ks * 2 + lhi) * 512 + lrow * 16);

    // staging: wave w owns chunk (pl=w>>1, kgl=w&1) of each slice
    auto ISSUE = [&](int s, int slotOff) {
        const int mtn = s >> 3, ksn = s & 7;
        const char* src = atile0 + (size_t)(mtn >> 2) * 131072 + (w >> 1) * 65536
                        + (ksn * 2 + (w & 1)) * 4096 + ((mtn & 3) * 64 + lane) * 16;
        char* dst = &lds[slotOff + (w >> 1) * 2048 + (w & 1) * 1024];
        __builtin_amdgcn_global_load_lds(
            (const __attribute__((address_space(1))) void*)src,
            (__attribute__((address_space(3))) void*)dst, 16, 0, 0);
    };

    i32x16 accH[2][2], accX[2][2];
#pragma unroll
    for (int ap = 0; ap < 2; ++ap)
#pragma unroll
        for (int bp = 0; bp < 2; ++bp) { accH[ap][bp] = (i32x16)(0); accX[ap][bp] = (i32x16)(0); }
    float rm[2], rz[2], rsu[2], rsv[2];
#pragma unroll
    for (int bp = 0; bp < 2; ++bp) { rm[bp] = -INFINITY; rz[bp] = 0.f; rsu[bp] = 0.f; rsv[bp] = 0.f; }

    const float S2 = 100.0f * 1.4426950408889634f / 1073741824.0f;  // 100*log2e/2^30
    const float cH = 65536.0f * S2;
    const float cX = 256.0f * S2;

    ISSUE(0, 0);
    ISSUE(1, 4096);
    int slotR = 0, slotW = 8192;               // read slot of s, write slot of s+2

    for (int mt = 0; mt < 16; ++mt) {
#pragma unroll
        for (int ks = 0; ks < 8; ++ks) {
            const int s = mt * 8 + ks;
            if (s < 127) asm volatile("s_waitcnt vmcnt(1)" ::: "memory");  // slice s drained
            else         asm volatile("s_waitcnt vmcnt(0)" ::: "memory");
            asm volatile("s_barrier" ::: "memory");
            if (s + 2 < 128) ISSUE(s + 2, slotW);

            i32x4 b0F[2];
#pragma unroll
            for (int bp = 0; bp < 2; ++bp)
                b0F[bp] = *(const i32x4*)&lds[B0OFF + (2 * w + bp) * 8192
                                              + (ks * 2 + lhi) * 512 + lrow * 16];
            i32x4 aF[2][2];
#pragma unroll
            for (int pl = 0; pl < 2; ++pl)
#pragma unroll
                for (int ap = 0; ap < 2; ++ap)
                    aF[pl][ap] = *(const i32x4*)&lds[slotR + pl * 2048 + lhi * 1024
                                                     + (ap * 32 + lrow) * 16];
            __builtin_amdgcn_s_setprio(1);
#pragma unroll
            for (int ap = 0; ap < 2; ++ap)
#pragma unroll
                for (int bp = 0; bp < 2; ++bp) {
                    accH[ap][bp] = __builtin_amdgcn_mfma_i32_32x32x32_i8(aF[0][ap], bc[ks][bp], accH[ap][bp], 0, 0, 0);
                    accX[ap][bp] = __builtin_amdgcn_mfma_i32_32x32x32_i8(aF[0][ap], b0F[bp],    accX[ap][bp], 0, 0, 0);
                    accX[ap][bp] = __builtin_amdgcn_mfma_i32_32x32x32_i8(aF[1][ap], bc[ks][bp], accX[ap][bp], 0, 0, 0);
                }
            __builtin_amdgcn_s_setprio(0);
            slotR = (slotR == 8192) ? 0 : slotR + 4096;
            slotW = (slotW == 8192) ? 0 : slotW + 4096;
        }

        // ---- epilogue for m-tile mt (64 rows x this wave's 64 n) ----
        const int mbase = mchunk * 1024 + mt * 64;
        const float ub0 = (float)((mbase & 255) + 4 * lhi);
        const float ub1 = ub0 + 32.0f;
        const float vcoord = (float)(mbase >> 8);
#pragma unroll
        for (int bp = 0; bp < 2; ++bp) {
            int hm = accH[0][bp][0];
#pragma unroll
            for (int ap = 0; ap < 2; ++ap)
#pragma unroll
                for (int r = 0; r < 16; ++r) {
                    int h = accH[ap][bp][r];
                    hm = (h > hm) ? h : hm;
                }
            const float bx = (float)hm * cH;
            float tz0 = 0.f, tz1 = 0.f, tsur = 0.f;
#pragma unroll
            for (int ap = 0; ap < 2; ++ap)
#pragma unroll
                for (int r = 0; r < 16; ++r) {
                    int dH = accH[ap][bp][r] - hm;                 // exact
                    float e = fexp2(fmaf((float)dH, cH, (float)accX[ap][bp][r] * cX));
                    if (ap == 0) tz0 += e; else tz1 += e;
                    tsur = fmaf(e, (float)((r & 3) + 8 * (r >> 2)), tsur);
                }
            float tzz = tz0 + tz1;
            float tsu = fmaf(ub0, tz0, fmaf(ub1, tz1, tsur));
            float tsv = vcoord * tzz;
            float nm = fmaxf(rm[bp], bx);
            float f1 = fexp2(rm[bp] - nm), f2 = fexp2(bx - nm);
            rz[bp]  = rz[bp]  * f1 + tzz * f2;
            rsu[bp] = rsu[bp] * f1 + tsu * f2;
            rsv[bp] = rsv[bp] * f1 + tsv * f2;
            rm[bp]  = nm;
#pragma unroll
            for (int ap = 0; ap < 2; ++ap) { accH[ap][bp] = (i32x16)(0); accX[ap][bp] = (i32x16)(0); }
        }
    }

    // ---- merge lane <-> lane+32 (same column, other row half), write partials ----
#pragma unroll
    for (int bp = 0; bp < 2; ++bp) {
        float m2  = __shfl_xor(rm[bp], 32, 64);
        float z2  = __shfl_xor(rz[bp], 32, 64);
        float su2 = __shfl_xor(rsu[bp], 32, 64);
        float sv2 = __shfl_xor(rsv[bp], 32, 64);
        float nm = fmaxf(rm[bp], m2);
        float f1 = fexp2(rm[bp] - nm), f2 = fexp2(m2 - nm);
        rz[bp]  = rz[bp]  * f1 + z2  * f2;
        rsu[bp] = rsu[bp] * f1 + su2 * f2;
        rsv[bp] = rsv[bp] * f1 + sv2 * f2;
        rm[bp]  = nm;
    }
    if (lane < 32) {
#pragma unroll
        for (int bp = 0; bp < 2; ++bp) {
            int n = nchunk * 256 + w * 64 + bp * 32 + lrow;
            size_t idxp = ((size_t)b * NN + n) * 64 + mchunk;
            ((float4*)partials)[idxp] = make_float4(rm[bp], rz[bp], rsu[bp], rsv[bp]);
        }
    }
}

// ---------------- combine: one wave per (b,n) row, 64 partials each ----------------
__global__ __launch_bounds__(256)
void combine_kernel(const float* __restrict__ partials,
                    const float* __restrict__ kscores,
                    const float* __restrict__ times,
                    float* __restrict__ out) {
    const int wg   = blockIdx.x * 4 + (threadIdx.x >> 6);  // 0..2047 = (b, n)
    const int lane = threadIdx.x & 63;
    const int b = wg >> 10, n = wg & 1023;
    const float4* pp = (const float4*)partials + (size_t)wg * 64;

    float4 p = pp[lane];
    float m = p.x, z = p.y, su = p.z, sv = p.w;
#pragma unroll
    for (int mask = 32; mask >= 1; mask >>= 1) {
        float m2  = __shfl_xor(m, mask, 64);
        float z2  = __shfl_xor(z, mask, 64);
        float su2 = __shfl_xor(su, mask, 64);
        float sv2 = __shfl_xor(sv, mask, 64);
        float nm = fmaxf(m, m2);
        float f1 = fexp2(m - nm), f2 = fexp2(m2 - nm);
        z = z * f1 + z2 * f2; su = su * f1 + su2 * f2; sv = sv * f1 + sv2 * f2; m = nm;
    }

    if (lane == 0) {
        float u = su / z, v = sv / z;
        out[(size_t)wg * 2 + 0] = u;
        out[(size_t)wg * 2 + 1] = v;
        out[4096 + wg] = kscores[(size_t)(2 * b + 1) * NN + n];
        if (wg == 0) { out[6144] = 1.0f; out[6145] = 3.0f; }

        const float* timg = times + (size_t)(2 * b) * MM;
        float u0 = fminf(fmaxf(floorf(u), 0.f), 255.f);
        float v0 = fminf(fmaxf(floorf(v), 0.f), 255.f);
        float u1 = fminf(u0 + 1.f, 255.f);
        float v1 = fminf(v0 + 1.f, 255.f);
        float au = u - u0, av = v - v0;
        int u0i = (int)u0, u1i = (int)u1, v0i = (int)v0, v1i = (int)v1;
        float t00 = timg[v0i * 256 + u0i], t01 = timg[v0i * 256 + u1i];
        float t10 = timg[v1i * 256 + u0i], t11 = timg[v1i * 256 + u1i];
        float t = t00 * (1.f - au) * (1.f - av) + t01 * au * (1.f - av)
                + t10 * (1.f - au) * av + t11 * au * av;
        out[6146 + wg] = t;
    }
}

extern "C" void kernel_launch(void* const* d_in, const int* in_sizes, int n_in,
                              void* d_out, int out_size, void* d_ws, size_t ws_size,
                              hipStream_t stream) {
    const float* kscores = (const float*)d_in[0];
    const float* kdesc   = (const float*)d_in[1];
    const float* dense   = (const float*)d_in[2];
    const float* times   = (const float*)d_in[3];
    float* out = (float*)d_out;

    char* Ag = (char*)d_ws;                                   // 67,108,864 B
    char* Bg = Ag + (size_t)2 * 256 * 131072;                 //  1,048,576 B
    float* partials = (float*)(Bg + (size_t)2 * 32 * 16384);  //  2,097,152 B

    hipFuncSetAttribute((const void*)gemm_kernel,
                        hipFuncAttributeMaxDynamicSharedMemorySize, 77824);

    hipLaunchKernelGGL(convB_kernel,   dim3(1024), dim3(512), 0, stream, dense, Ag);
    hipLaunchKernelGGL(convA_kernel,   dim3(64),   dim3(256), 0, stream, kdesc, Bg);
    hipLaunchKernelGGL(gemm_kernel,    dim3(512),  dim3(256), 77824, stream, Ag, Bg, partials);
    hipLaunchKernelGGL(combine_kernel, dim3(512),  dim3(256), 0, stream, partials, kscores, times, out);
}